// Round 7
// baseline (263.101 us; speedup 1.0000x reference)
//
#include <hip/hip_runtime.h>
#include <stdint.h>

typedef float f32x4 __attribute__((ext_vector_type(4)));
typedef short bf16x8 __attribute__((ext_vector_type(8)));

__device__ __forceinline__ float bf2f(unsigned short h){
  union { unsigned int u; float f; } v; v.u = ((unsigned int)h) << 16; return v.f;
}
__device__ __forceinline__ unsigned short f2bf(float f){
  union { float f; unsigned int u; } v; v.f = f;
  return (unsigned short)((v.u + 0x7fffu + ((v.u >> 16) & 1u)) >> 16);
}

typedef __attribute__((address_space(1))) const unsigned int ga_u32;
typedef __attribute__((address_space(3))) unsigned int ls_u32;
__device__ __forceinline__ void async_load16(const void* g, void* l){
  __builtin_amdgcn_global_load_lds((ga_u32*)g, (ls_u32*)l, 16, 0, 0);
}

#define CFENCE() asm volatile("" ::: "memory")
#define SB0() __builtin_amdgcn_sched_barrier(0)

// ---------------------------------------------------------------------------
// prep: fp32 weights -> bf16 (5 x 512x512), biases -> packed fp32 [5][512]
__global__ __launch_bounds__(256) void k_prep_w(
    const float* __restrict__ w0, const float* __restrict__ w1,
    const float* __restrict__ w2, const float* __restrict__ w3,
    const float* __restrict__ w4, unsigned short* __restrict__ out)
{
  int i = blockIdx.x * 256 + threadIdx.x;
  const float* w = (blockIdx.y == 0) ? w0 : (blockIdx.y == 1) ? w1 :
                   (blockIdx.y == 2) ? w2 : (blockIdx.y == 3) ? w3 : w4;
  out[(size_t)blockIdx.y * 262144 + i] = f2bf(w[i]);
}
__global__ __launch_bounds__(256) void k_prep_b(
    const float* __restrict__ b0, const float* __restrict__ b1,
    const float* __restrict__ b2, const float* __restrict__ b3,
    const float* __restrict__ b4, float* __restrict__ out)
{
  int i = blockIdx.x * 256 + threadIdx.x;   // 0..2559
  int s = i >> 9, r = i & 511;
  const float* b = (s == 0) ? b0 : (s == 1) ? b1 : (s == 2) ? b2 : (s == 3) ? b3 : b4;
  out[i] = b[r];
}

// ---------------------------------------------------------------------------
// build xs_bf[b][l][c] AND xsT[b][c][l] = bf16( x[b][c][l] + pos[l][c] )
__global__ __launch_bounds__(256) void k_build_xs(
    const float* __restrict__ x, const float* __restrict__ pos,
    unsigned short* __restrict__ xsb, unsigned short* __restrict__ xsT)
{
  __shared__ float tile[64][65];
  __shared__ unsigned short tile2[64][72];
  const int lt = blockIdx.x, ct = blockIdx.y, b = blockIdx.z;
  const int t = threadIdx.x;
  const int rr = t >> 3, c8 = (t & 7) * 8;
  #pragma unroll
  for (int pass = 0; pass < 2; pass++){
    int r = rr + pass * 32;
    const float* src = x + ((size_t)b * 512 + ct*64 + r) * 4096 + lt*64 + c8;
    f32x4 v0 = *(const f32x4*)src;
    f32x4 v1 = *(const f32x4*)(src + 4);
    #pragma unroll
    for (int s = 0; s < 4; s++){ tile[r][c8+s] = v0[s]; tile[r][c8+4+s] = v1[s]; }
  }
  __syncthreads();
  #pragma unroll
  for (int pass = 0; pass < 2; pass++){
    int ll = rr + pass * 32;
    int gl = lt*64 + ll;
    const float* pp = pos + (size_t)gl * 512 + ct*64 + c8;
    bf16x8 hv;
    #pragma unroll
    for (int s = 0; s < 8; s++){
      unsigned short h = f2bf(tile[c8+s][ll] + pp[s]);
      hv[s] = (short)h;
      tile2[c8+s][ll] = h;
    }
    *(bf16x8*)(xsb + ((size_t)b * 4096 + gl) * 512 + ct*64 + c8) = hv;
  }
  __syncthreads();
  #pragma unroll
  for (int rep = 0; rep < 2; rep++){
    int c = rep*32 + (t >> 3);
    int l0 = (t & 7) * 8;
    bf16x8 v = *(const bf16x8*)&tile2[c][l0];
    *(bf16x8*)(xsT + ((size_t)b * 512 + ct*64 + c) * 4096 + lt*64 + l0) = v;
  }
}

// ---------------------------------------------------------------------------
// s[b][c] = sum_l xsT[b][c][l]
__global__ __launch_bounds__(256) void k_colsum(
    const unsigned short* __restrict__ xsT, float* __restrict__ svec)
{
  const int cblk = blockIdx.x, b = blockIdx.y;
  const int t = threadIdx.x;
  const int wave = t >> 6, lane = t & 63;
  for (int rr = 0; rr < 16; rr++){
    int c = cblk*64 + wave*16 + rr;
    const unsigned short* row = xsT + ((size_t)b * 512 + c) * 4096;
    float a[8] = {0.f,0.f,0.f,0.f,0.f,0.f,0.f,0.f};
    #pragma unroll
    for (int pass = 0; pass < 8; pass++){
      bf16x8 v = *(const bf16x8*)(row + pass*512 + lane*8);
      #pragma unroll
      for (int j = 0; j < 8; j++) a[j] += bf2f((unsigned short)v[j]);
    }
    float sum = a[0]+a[1]+a[2]+a[3]+a[4]+a[5]+a[6]+a[7];
    #pragma unroll
    for (int m = 1; m < 64; m <<= 1) sum += __shfl_xor(sum, m);
    if (lane == 0) svec[b*512 + c] = sum;
  }
}

// ---------------------------------------------------------------------------
// u[b][e] = Wq1 . s   (sel 0)    w[b][d] = Wk1 . s  (sel 1)
__global__ __launch_bounds__(256) void k_uw(
    const unsigned short* __restrict__ wbf, const float* __restrict__ svec,
    float* __restrict__ u, float* __restrict__ w)
{
  __shared__ float sv[512];
  const int sel = blockIdx.x, b = blockIdx.y;
  const int t = threadIdx.x;
  sv[t] = svec[b*512 + t]; sv[t+256] = svec[b*512 + t + 256];
  __syncthreads();
  const unsigned short* Wp = wbf + (size_t)(3 + sel) * 262144;
  float* o = sel ? w : u;
  #pragma unroll
  for (int rep = 0; rep < 2; rep++){
    int e = rep*256 + t;
    const unsigned short* row = Wp + (size_t)e * 512;
    float acc = 0.f;
    for (int ch = 0; ch < 64; ch++){
      bf16x8 v = *(const bf16x8*)(row + ch*8);
      #pragma unroll
      for (int j = 0; j < 8; j++) acc += bf2f((unsigned short)v[j]) * sv[ch*8+j];
    }
    o[b*512 + e] = acc;
  }
}

// ---------------------------------------------------------------------------
// Gbf = bf16(Gp0 + Gp1)
__global__ __launch_bounds__(256) void k_combineG(
    const float* __restrict__ g0, const float* __restrict__ g1,
    unsigned short* __restrict__ gb)
{
  size_t i8 = ((size_t)blockIdx.x * 256 + threadIdx.x) * 8;
  f32x4 a0 = *(const f32x4*)(g0 + i8)     + *(const f32x4*)(g1 + i8);
  f32x4 a1 = *(const f32x4*)(g0 + i8 + 4) + *(const f32x4*)(g1 + i8 + 4);
  bf16x8 hv;
  #pragma unroll
  for (int s = 0; s < 4; s++){ hv[s] = (short)f2bf(a0[s]); hv[4+s] = (short)f2bf(a1[s]); }
  *(bf16x8*)(gb + i8) = hv;
}

// ---------------------------------------------------------------------------
// Z[row] = 1 / sum_c Q[row,c]*(Ksum[b,c]+eps)
__global__ __launch_bounds__(256) void k_z(
    const unsigned short* __restrict__ Qb, const float* __restrict__ ksum,
    float* __restrict__ Z)
{
  const int row = blockIdx.x * 4 + (threadIdx.x >> 6);
  const int lane = threadIdx.x & 63;
  const int b = row >> 12;
  bf16x8 q = *(const bf16x8*)(Qb + (size_t)row * 512 + lane * 8);
  f32x4 k0 = *(const f32x4*)(ksum + b*512 + lane*8);
  f32x4 k1 = *(const f32x4*)(ksum + b*512 + lane*8 + 4);
  float den = 0.f;
  #pragma unroll
  for (int s = 0; s < 4; s++) den += bf2f((unsigned short)q[s])   * (k0[s] + 1e-6f);
  #pragma unroll
  for (int s = 0; s < 4; s++) den += bf2f((unsigned short)q[4+s]) * (k1[s] + 1e-6f);
  #pragma unroll
  for (int m = 1; m < 64; m <<= 1) den += __shfl_xor(den, m);
  if (lane == 0) Z[row] = 1.0f / den;
}

// ---------------------------------------------------------------------------
// row softmax: S[row][0..511] fp32 -> mid bf16
__global__ __launch_bounds__(64) void k_softmax(
    const float* __restrict__ S, unsigned short* __restrict__ mid)
{
  const size_t row = blockIdx.x;
  const int lane = threadIdx.x;
  const float* p = S + row * 512 + lane * 8;
  f32x4 v0 = *(const f32x4*)p, v1 = *(const f32x4*)(p + 4);
  float mx = v0[0];
  #pragma unroll
  for (int s = 1; s < 4; s++) mx = fmaxf(mx, v0[s]);
  #pragma unroll
  for (int s = 0; s < 4; s++) mx = fmaxf(mx, v1[s]);
  #pragma unroll
  for (int m = 1; m < 64; m <<= 1) mx = fmaxf(mx, __shfl_xor(mx, m));
  float e[8]; float sum = 0.f;
  #pragma unroll
  for (int s = 0; s < 4; s++){ e[s]   = __expf(v0[s] - mx); sum += e[s]; }
  #pragma unroll
  for (int s = 0; s < 4; s++){ e[4+s] = __expf(v1[s] - mx); sum += e[4+s]; }
  #pragma unroll
  for (int m = 1; m < 64; m <<= 1) sum += __shfl_xor(sum, m);
  float inv = 1.0f / sum;
  bf16x8 hv;
  #pragma unroll
  for (int s = 0; s < 8; s++) hv[s] = (short)f2bf(e[s] * inv);
  *(bf16x8*)(mid + row * 512 + lane * 8) = hv;
}

// ---------------------------------------------------------------------------
// mid transpose with diag fold: midT[z][d][c] = mid[z][c][d] * diag[z][c]
__global__ __launch_bounds__(256) void k_transpose_scale(
    const unsigned short* __restrict__ in, const float* __restrict__ diag,
    unsigned short* __restrict__ out)
{
  __shared__ float tile[64][65];
  const int rt = blockIdx.x, ct = blockIdx.y, z = blockIdx.z;
  const unsigned short* src = in  + (size_t)z * 262144;
  unsigned short*       dst = out + (size_t)z * 262144;
  const int t = threadIdx.x;
  const int rr = t >> 3, c8 = (t & 7) * 8;
  #pragma unroll
  for (int pass = 0; pass < 2; pass++){
    int r = rr + pass * 32;
    bf16x8 v = *(const bf16x8*)(src + (size_t)(rt*64 + r) * 512 + ct*64 + c8);
    #pragma unroll
    for (int s = 0; s < 8; s++) tile[r][c8+s] = bf2f((unsigned short)v[s]);
  }
  __syncthreads();
  f32x4 dg0 = *(const f32x4*)(diag + z*512 + rt*64 + c8);
  f32x4 dg1 = *(const f32x4*)(diag + z*512 + rt*64 + c8 + 4);
  #pragma unroll
  for (int pass = 0; pass < 2; pass++){
    int c = rr + pass * 32;
    bf16x8 hv;
    #pragma unroll
    for (int s = 0; s < 4; s++) hv[s]   = (short)f2bf(tile[c8+s][c]   * dg0[s]);
    #pragma unroll
    for (int s = 0; s < 4; s++) hv[4+s] = (short)f2bf(tile[c8+4+s][c] * dg1[s]);
    *(bf16x8*)(dst + (size_t)(ct*64 + c) * 512 + rt*64 + c8) = hv;
  }
}

// ===========================================================================
// 128x128-tile 2-phase GEMM machinery (64KB LDS -> 2 blocks/CU).
// ===========================================================================
#define GEMM_PRE()                                                            \
  const int tid = threadIdx.x;                                                \
  const int lane = tid & 63;                                                  \
  const int wave = tid >> 6;                                                  \
  const int wm = wave >> 1, wn = wave & 1;                                    \
  size_t aoff[4], boff[4]; int ldsq[4];                                       \
  _Pragma("unroll")                                                           \
  for (int i = 0; i < 4; i++){                                                \
    int qq = i*4 + wave;                                                      \
    int ch = qq*64 + lane;                                                    \
    int m  = ch >> 3, p = ch & 7;                                             \
    int lc = p ^ (m & 7);                                                     \
    aoff[i] = (size_t)(m0 + m) * K + lc*8;                                    \
    boff[i] = (size_t)m * K + lc*8;                                           \
    ldsq[i] = qq * 1024;                                                      \
  }                                                                           \
  f32x4 acc[4][4];                                                            \
  const f32x4 vzero = {0.f,0.f,0.f,0.f};                                      \
  _Pragma("unroll")                                                           \
  for (int i = 0; i < 4; i++)                                                 \
    _Pragma("unroll")                                                         \
    for (int j = 0; j < 4; j++) acc[i][j] = vzero;                            \
  int arow[4], brow[4];                                                       \
  _Pragma("unroll")                                                           \
  for (int f = 0; f < 4; f++){                                                \
    arow[f] = (wm*64 + f*16 + (lane & 15)) * 64;                              \
    brow[f] = (wn*64 + f*16 + (lane & 15)) * 64;                              \
  }                                                                           \
  const int kg = lane >> 4;                                                   \
  const int l7 = lane & 7;                                                    \
  const int l15 = lane & 15;

#define GEMM_STAGE2(buf, kt, BB)                                              \
  _Pragma("unroll")                                                           \
  for (int i = 0; i < 4; i++){                                                \
    async_load16(Ae + aoff[i] + (kt)*64, (char*)&smem[(buf)*8192] + ldsq[i]); \
    async_load16((BB) + boff[i] + (kt)*64, (char*)&smem[16384 + (buf)*8192] + ldsq[i]); \
  }

#define GEMM_COMPUTE2(buf, ACC)                                               \
  _Pragma("unroll")                                                           \
  for (int ks = 0; ks < 2; ks++){                                             \
    bf16x8 a[4], b[4];                                                        \
    const int pa = (ks*4 + kg) ^ l7;                                          \
    _Pragma("unroll")                                                         \
    for (int f = 0; f < 4; f++){                                              \
      a[f] = *(const bf16x8*)&smem[(buf)*8192 + arow[f] + pa*8];              \
      b[f] = *(const bf16x8*)&smem[16384 + (buf)*8192 + brow[f] + pa*8];      \
    }                                                                         \
    _Pragma("unroll")                                                         \
    for (int i = 0; i < 4; i++)                                               \
      _Pragma("unroll")                                                       \
      for (int j = 0; j < 4; j++)                                             \
        (ACC)[i][j] = __builtin_amdgcn_mfma_f32_16x16x32_bf16(a[i], b[j], (ACC)[i][j], 0, 0, 0); \
  }

#define GEMM_KLOOP2(nkt, BB)                                                  \
  GEMM_STAGE2(0, 0, BB);                                                      \
  __syncthreads();                                                            \
  { int cur = 0;                                                              \
    for (int kt = 0; kt < (nkt); kt++){                                       \
      if (kt + 1 < (nkt)) { GEMM_STAGE2(cur ^ 1, kt + 1, BB); }               \
      GEMM_COMPUTE2(cur, acc);                                                \
      __syncthreads();                                                        \
      cur ^= 1;                                                               \
    } }

// ---------------------------------------------------------------------------
// G syrk split-K: Gpart[b][c1][c2] = sum_{l in part} xsT[b,c1,l]*xsT[b,c2,l]
__global__ __launch_bounds__(256) void gemm_G(
    const unsigned short* __restrict__ A,
    float* __restrict__ out0, float* __restrict__ out1)
{
  __shared__ unsigned short smem[32768];
  const int bid = blockIdx.x;
  const int wgid = (bid & 7) * 32 + (bid >> 3);    // 256 blocks
  const int part = wgid & 1;
  const int ntile = (wgid >> 1) & 3;
  const int mtile = (wgid >> 3) & 3;
  const int z = wgid >> 5;
  const int m0 = mtile * 128, n0 = ntile * 128;
  const int K = 4096;
  const unsigned short* Ae = A + (size_t)z * 2097152 + part * 2048;
  const unsigned short* Be = Ae + (size_t)n0 * 4096;

  GEMM_PRE();
  GEMM_KLOOP2(32, Be);

  float* outf = part ? out1 : out0;
  #pragma unroll
  for (int j = 0; j < 4; j++){
    int cidx = n0 + wn*64 + j*16 + l15;
    #pragma unroll
    for (int i = 0; i < 4; i++){
      int r = m0 + wm*64 + i*16 + kg*4;
      #pragma unroll
      for (int q = 0; q < 4; q++)
        outf[(size_t)z * 262144 + (size_t)(r + q) * 512 + cidx] = acc[i][j][q];
    }
  }
}

// ---------------------------------------------------------------------------
// P[z] = Wq1 @ G[z]  (G symmetric -> bt-form). 128 blocks, K=512.
__global__ __launch_bounds__(256) void gemm_P(
    const unsigned short* __restrict__ Wq1b,
    const unsigned short* __restrict__ Gb,
    unsigned short* __restrict__ P)
{
  __shared__ unsigned short smem[32768];
  const int bid = blockIdx.x;
  const int wgid = (bid & 7) * 16 + (bid >> 3);    // 128 blocks
  const int z = wgid >> 4;
  const int mtile = (wgid >> 2) & 3, ntile = wgid & 3;
  const int m0 = mtile * 128, n0 = ntile * 128;
  const int K = 512;
  const unsigned short* Ae = Wq1b;
  const unsigned short* Be = Gb + (size_t)z * 262144 + (size_t)n0 * 512;

  GEMM_PRE();
  GEMM_KLOOP2(8, Be);

  #pragma unroll
  for (int j = 0; j < 4; j++){
    const int cl = wn*64 + j*16 + l15;
    #pragma unroll
    for (int i = 0; i < 4; i++){
      const int rb = wm*64 + i*16 + kg*4;
      #pragma unroll
      for (int q = 0; q < 4; q++)
        smem[(rb + q)*136 + cl] = f2bf(acc[i][j][q]);
    }
  }
  __syncthreads();
  #pragma unroll
  for (int rep = 0; rep < 8; rep++){
    const int rl = rep*16 + (tid >> 4);
    const int c0 = (tid & 15) * 8;
    bf16x8 v = *(const bf16x8*)&smem[rl*136 + c0];
    *(bf16x8*)(P + (size_t)z * 262144 + (size_t)(m0 + rl) * 512 + n0 + c0) = v;
  }
}

// ---------------------------------------------------------------------------
// S[z] = P[z] @ Wk1^T + u bk1^T + bq1 w^T + L bq1 bk1^T  (fp32 out)
__global__ __launch_bounds__(256) void gemm_S(
    const unsigned short* __restrict__ P,
    const unsigned short* __restrict__ Wk1b,
    const float* __restrict__ bias5,
    const float* __restrict__ u, const float* __restrict__ w,
    float* __restrict__ Sf)
{
  __shared__ unsigned short smem[32768];
  const int bid = blockIdx.x;
  const int wgid = (bid & 7) * 16 + (bid >> 3);    // 128 blocks
  const int z = wgid >> 4;
  const int mtile = (wgid >> 2) & 3, ntile = wgid & 3;
  const int m0 = mtile * 128, n0 = ntile * 128;
  const int K = 512;
  const unsigned short* Ae = P + (size_t)z * 262144;
  const unsigned short* Be = Wk1b + (size_t)n0 * 512;

  GEMM_PRE();
  GEMM_KLOOP2(8, Be);

  #pragma unroll
  for (int j = 0; j < 4; j++){
    int cd = n0 + wn*64 + j*16 + l15;
    float bkv = bias5[2048 + cd];
    float wv  = w[z*512 + cd] + 4096.0f * bkv;
    #pragma unroll
    for (int i = 0; i < 4; i++){
      int r = m0 + wm*64 + i*16 + kg*4;
      #pragma unroll
      for (int q = 0; q < 4; q++){
        int rr = r + q;
        float uq  = u[z*512 + rr];
        float bqv = bias5[1536 + rr];
        Sf[(size_t)z * 262144 + (size_t)rr * 512 + cd] =
            acc[i][j][q] + uq * bkv + bqv * wv;
      }
    }
  }
}

// ---------------------------------------------------------------------------
// fused projections, 128² tiles, 2 blocks/CU. grid = 2048.
// unit 0..3: Q cols unit*128 (relu); 4..7: chained K+V pair p=unit-4.
__global__ __launch_bounds__(256, 2) void gemm_proj2(
    const unsigned short* __restrict__ A,
    const unsigned short* __restrict__ W,
    const float* __restrict__ bias5,
    unsigned short* __restrict__ Qb,
    float* __restrict__ diag, float* __restrict__ ksum)
{
  __shared__ unsigned short smem[32768];   // 64KB
  const int bid = blockIdx.x;
  const int wgid = (bid & 7) * 256 + (bid >> 3);   // 2048 % 8 == 0: bijective
  const int mtile = wgid >> 3;                     // 0..255
  const int unit  = wgid & 7;
  const int m0 = mtile * 128;
  const int K = 512;
  const unsigned short* Ae = A;

  int mode, cb;
  const unsigned short* BeK; const unsigned short* BeV = W;
  if (unit < 4){ mode = 0; cb = unit*128;     BeK = W + (size_t)cb * 512; }
  else         { mode = 1; cb = (unit-4)*128; BeK = W + 262144 + (size_t)cb * 512;
                                              BeV = W + 524288 + (size_t)cb * 512; }

  GEMM_PRE();

  if (mode == 1){
    const int bz = mtile >> 5;
    // --- K-phase ---
    GEMM_STAGE2(0, 0, BeK);
    __syncthreads();
    int cur = 0;
    for (int kt = 0; kt < 8; kt++){
      if (kt < 7) { GEMM_STAGE2(cur ^ 1, kt + 1, BeK); }
      else        { GEMM_STAGE2(cur ^ 1, 0, BeV); }
      GEMM_COMPUTE2(cur, acc);
      __syncthreads();
      cur ^= 1;
    }
    GEMM_STAGE2(cur ^ 1, 1, BeV);     // prefetch V kt1 during pack
    // pack relu'd K to bf16 regs + Ksum partial atomics
    unsigned int kpk[4][4][2];
    #pragma unroll
    for (int j = 0; j < 4; j++){
      const int cj = cb + wn*64 + j*16 + l15;
      const float bb = bias5[512 + cj];
      float ks_ = 0.f;
      #pragma unroll
      for (int i = 0; i < 4; i++){
        #pragma unroll
        for (int h = 0; h < 2; h++){
          float v0 = acc[i][j][2*h]   + bb; v0 = v0 > 0.f ? v0 : 0.f;
          float v1 = acc[i][j][2*h+1] + bb; v1 = v1 > 0.f ? v1 : 0.f;
          unsigned short h0 = f2bf(v0), h1 = f2bf(v1);
          kpk[i][j][h] = (unsigned)h0 | ((unsigned)h1 << 16);
          ks_ += bf2f(h0) + bf2f(h1);
        }
        acc[i][j] = vzero;
      }
      ks_ += __shfl_xor(ks_, 16);
      ks_ += __shfl_xor(ks_, 32);
      if (lane < 16) atomicAdd(&ksum[bz*512 + cj], ks_);
    }
    // --- V-phase (pipeline continues) ---
    for (int kt = 0; kt < 8; kt++){
      if (kt >= 1 && kt < 7) { GEMM_STAGE2(cur ^ 1, kt + 1, BeV); }
      GEMM_COMPUTE2(cur, acc);
      __syncthreads();
      cur ^= 1;
    }
    #pragma unroll
    for (int j = 0; j < 4; j++){
      const int cj = cb + wn*64 + j*16 + l15;
      const float bb = bias5[1024 + cj];
      float dv = 0.f;
      #pragma unroll
      for (int i = 0; i < 4; i++){
        #pragma unroll
        for (int h = 0; h < 2; h++){
          float v0 = bf2f(f2bf(acc[i][j][2*h]   + bb));
          float v1 = bf2f(f2bf(acc[i][j][2*h+1] + bb));
          dv += bf2f((unsigned short)(kpk[i][j][h] & 0xffffu)) * v0
              + bf2f((unsigned short)(kpk[i][j][h] >> 16))     * v1;
        }
      }
      dv += __shfl_xor(dv, 16);
      dv += __shfl_xor(dv, 32);
      if (lane < 16) atomicAdd(&diag[bz*512 + cj], dv);
    }
    return;
  }

  GEMM_KLOOP2(8, BeK);

  #pragma unroll
  for (int j = 0; j < 4; j++){
    const int cl = wn*64 + j*16 + l15;
    const float bb = bias5[cb + cl];
    #pragma unroll
    for (int i = 0; i < 4; i++){
      const int rb = wm*64 + i*16 + kg*4;
      #pragma unroll
      for (int q = 0; q < 4; q++){
        float v = acc[i][j][q] + bb; v = v > 0.f ? v : 0.f;
        smem[(rb + q)*136 + cl] = f2bf(v);
      }
    }
  }
  __syncthreads();
  #pragma unroll
  for (int rep = 0; rep < 8; rep++){
    const int rl = rep*16 + (tid >> 4);
    const int c0 = (tid & 15) * 8;
    bf16x8 v = *(const bf16x8*)&smem[rl*136 + c0];
    *(bf16x8*)(Qb + (size_t)(m0 + rl) * 512 + cb + c0) = v;
  }
}

// ===========================================================================
// 256x256-tile, 8-wave, 8-phase counted-vmcnt GEMM (result GEMM only).
// ===========================================================================
#define G8_PRE(AE)                                                            \
  const int t = threadIdx.x;                                                  \
  const int lane = t & 63;                                                    \
  const int wave = t >> 6;                                                    \
  const int wm = wave >> 2, wn = wave & 3;                                    \
  const int l15 = lane & 15, kg = lane >> 4;                                  \
  const int lcw = ((t & 7) ^ ((t >> 3) & 7)) * 8;                             \
  const unsigned short* a_src = (AE) + (size_t)(m0 + (t >> 3)) * 512 + lcw;   \
  f32x4 acc[8][4];                                                            \
  const f32x4 vzero = {0.f,0.f,0.f,0.f};                                      \
  _Pragma("unroll")                                                           \
  for (int i = 0; i < 8; i++)                                                 \
    _Pragma("unroll")                                                         \
    for (int j = 0; j < 4; j++) acc[i][j] = vzero;                            \
  bf16x8 af[4][2], bf[4][2];

#define STAGE_A(D,H,TT) do{                                                   \
  async_load16(a_src + (H)*65536 + (TT)*64,                                   \
               (char*)smem + ((D)*16384 + (H)*8192 + t*8)*2);                 \
  async_load16(a_src + (H)*65536 + 32768 + (TT)*64,                           \
               (char*)smem + ((D)*16384 + (H)*8192 + 4096 + t*8)*2);          \
}while(0)

#define STAGE_B(D,H,TT) do{                                                   \
  async_load16(b_src + (H)*65536 + (TT)*64,                                   \
               (char*)smem + (32768 + (D)*16384 + (H)*8192 + t*8)*2);         \
  async_load16(b_src + (H)*65536 + 32768 + (TT)*64,                           \
               (char*)smem + (32768 + (D)*16384 + (H)*8192 + 4096 + t*8)*2);  \
}while(0)

#define READ_A(D, MH) do{                                                     \
  _Pragma("unroll")                                                           \
  for (int mfl = 0; mfl < 4; ++mfl){                                          \
    const int rl = ((MH)*4 + mfl)*16 + l15;                                   \
    _Pragma("unroll")                                                         \
    for (int ks = 0; ks < 2; ++ks){                                           \
      const int ck = (ks*4 + kg) ^ (rl & 7);                                  \
      af[mfl][ks] = *(const bf16x8*)&smem[(D)*16384 + wm*8192 + rl*64 + ck*8];\
    }                                                                         \
  }                                                                           \
}while(0)

#define READ_B(D, NP) do{                                                     \
  _Pragma("unroll")                                                           \
  for (int nfl = 0; nfl < 2; ++nfl){                                          \
    const int nf = (NP)*2 + nfl;                                              \
    const int rbl = (wn & 1)*64 + nf*16 + l15;                                \
    _Pragma("unroll")                                                         \
    for (int ks = 0; ks < 2; ++ks){                                           \
      const int ck = (ks*4 + kg) ^ (rbl & 7);                                 \
      bf[nf][ks] = *(const bf16x8*)&smem[32768 + (D)*16384 + (wn>>1)*8192 + rbl*64 + ck*8]; \
    }                                                                         \
  }                                                                           \
}while(0)

#define QUAD(MH, NP)                                                          \
  _Pragma("unroll")                                                           \
  for (int mfl = 0; mfl < 4; ++mfl)                                           \
    _Pragma("unroll")                                                         \
    for (int nfl = 0; nfl < 2; ++nfl)                                         \
      _Pragma("unroll")                                                       \
      for (int ks = 0; ks < 2; ++ks)                                          \
        acc[(MH)*4+mfl][(NP)*2+nfl] = __builtin_amdgcn_mfma_f32_16x16x32_bf16(\
            af[mfl][ks], bf[(NP)*2+nfl][ks], acc[(MH)*4+mfl][(NP)*2+nfl], 0,0,0);

#define PH_MID()  CFENCE(); __builtin_amdgcn_s_barrier();                     \
  __builtin_amdgcn_s_setprio(1); SB0()
#define PH_END()  SB0(); __builtin_amdgcn_s_setprio(0); CFENCE();             \
  __builtin_amdgcn_s_barrier(); CFENCE()
#define PH_END_VM4() SB0(); __builtin_amdgcn_s_setprio(0);                    \
  asm volatile("s_waitcnt vmcnt(4)" ::: "memory");                            \
  __builtin_amdgcn_s_barrier(); CFENCE()
#define PH_END_VM0() SB0(); __builtin_amdgcn_s_setprio(0);                    \
  asm volatile("s_waitcnt vmcnt(0)" ::: "memory");                            \
  __builtin_amdgcn_s_barrier(); CFENCE()

#define G8_KLOOP()                                                            \
  STAGE_A(0,0,0); STAGE_A(0,1,0); STAGE_B(0,0,0); STAGE_B(0,1,0);             \
  STAGE_B(1,0,1); STAGE_B(1,1,1);                                             \
  asm volatile("s_waitcnt vmcnt(4)" ::: "memory");                            \
  __builtin_amdgcn_s_barrier(); CFENCE();                                     \
  for (int it = 0; it < 3; ++it){                                             \
    const int t1 = 2*it + 1, t2 = 2*it + 2, t3 = 2*it + 3;                    \
    READ_A(0,0); READ_B(0,0); STAGE_A(1,0,t1);                                \
    PH_MID(); QUAD(0,0); PH_END();                                            \
    READ_B(0,1); STAGE_A(1,1,t1);                                             \
    PH_MID(); QUAD(0,1); PH_END();                                            \
    READ_A(0,1); STAGE_B(0,0,t2);                                             \
    PH_MID(); QUAD(1,0); PH_END();                                            \
    STAGE_A(0,0,t2);                                                          \
    PH_MID(); QUAD(1,1); PH_END_VM4();                                        \
    READ_A(1,0); READ_B(1,0); STAGE_A(0,1,t2);                                \
    PH_MID(); QUAD(0,0); PH_END();                                            \
    READ_B(1,1); STAGE_B(0,1,t2);                                             \
    PH_MID(); QUAD(0,1); PH_END();                                            \
    READ_A(1,1); STAGE_B(1,0,t3);                                             \
    PH_MID(); QUAD(1,0); PH_END();                                            \
    STAGE_B(1,1,t3);                                                          \
    PH_MID(); QUAD(1,1); PH_END_VM4();                                        \
  }                                                                           \
  { READ_A(0,0); READ_B(0,0); STAGE_A(1,0,7);                                 \
    PH_MID(); QUAD(0,0); PH_END();                                            \
    READ_B(0,1); STAGE_A(1,1,7);                                              \
    PH_MID(); QUAD(0,1); PH_END();                                            \
    READ_A(0,1);                                                              \
    PH_MID(); QUAD(1,0); PH_END();                                            \
    PH_MID(); QUAD(1,1); PH_END_VM0();                                        \
    READ_A(1,0); READ_B(1,0);                                                 \
    PH_MID(); QUAD(0,0); PH_END();                                            \
    READ_B(1,1);                                                              \
    PH_MID(); QUAD(0,1); PH_END();                                            \
    READ_A(1,1);                                                              \
    PH_MID(); QUAD(1,0); PH_END();                                            \
    PH_MID(); QUAD(1,1); PH_END(); }

// ---------------------------------------------------------------------------
// result GEMM: y = xs + gamma*Z[l]*(Q @ midT'^T) in-place + BN stats.
__global__ __launch_bounds__(512, 2) void gemm8_res(
    const unsigned short* __restrict__ A,        // Qb [32768][512]
    const unsigned short* __restrict__ Bt,       // midT' [8][512][512]
    const float* __restrict__ Zp,                // [32768]
    unsigned short* __restrict__ outh,           // xs bf16, in-place -> y
    const float* __restrict__ gamma_p,
    float* __restrict__ bnS, float* __restrict__ bnQ)
{
  __shared__ unsigned short smem[65536];
  __shared__ float zbuf[256];
  const int bid = blockIdx.x;
  const int wgid = (bid & 7) * 32 + (bid >> 3);   // 256 % 8 == 0
  const int mtile = wgid >> 1;
  const int ntile = wgid & 1;
  const int m0 = mtile * 256;
  const int nc0 = ntile * 256;

  G8_PRE(A);
  const unsigned short* b_src =
      Bt + (size_t)(mtile >> 4) * 262144 + (size_t)(nc0 + (t >> 3)) * 512 + lcw;

  G8_KLOOP();

  const float g = gamma_p[0];
  __syncthreads();
  if (t < 256) zbuf[t] = Zp[m0 + t];
  __syncthreads();
  // stage 1: g*Z*acc -> LDS bf16 swizzled
  #pragma unroll
  for (int nf = 0; nf < 4; nf++){
    int cl = wn*64 + nf*16 + l15;
    #pragma unroll
    for (int mf = 0; mf < 8; mf++){
      int rbase = wm*128 + mf*16 + kg*4;
      #pragma unroll
      for (int q = 0; q < 4; q++){
        int rl = rbase + q;
        smem[rl*256 + (cl ^ (((rl >> 2) & 3) << 4))] =
            f2bf(g * zbuf[rl] * acc[mf][nf][q]);
      }
    }
  }
  __syncthreads();
  // stage 2: coalesced RMW + per-thread col partials
  float sc[8] = {0.f,0.f,0.f,0.f,0.f,0.f,0.f,0.f};
  float sq[8] = {0.f,0.f,0.f,0.f,0.f,0.f,0.f,0.f};
  const int c0 = (t & 31) * 8;
  #pragma unroll
  for (int rep = 0; rep < 16; rep++){
    int rl = rep*16 + (t >> 5);
    bf16x8 ga = *(const bf16x8*)&smem[rl*256 + (c0 ^ (((rl >> 2) & 3) << 4))];
    size_t gidx = (size_t)(m0 + rl) * 512 + nc0 + c0;
    bf16x8 xv = *(const bf16x8*)(outh + gidx);
    bf16x8 yv;
    #pragma unroll
    for (int j = 0; j < 8; j++){
      float y = bf2f((unsigned short)xv[j]) + bf2f((unsigned short)ga[j]);
      yv[j] = (short)f2bf(y);
      sc[j] += y; sq[j] += y * y;
    }
    *(bf16x8*)(outh + gidx) = yv;
  }
  __syncthreads();
  // stage 3: reduce col partials across 16 row-groups, then atomics
  float* red = (float*)(void*)smem;
  const int tg = t >> 5;
  f32x4 s0 = {sc[0],sc[1],sc[2],sc[3]}, s1 = {sc[4],sc[5],sc[6],sc[7]};
  f32x4 q0 = {sq[0],sq[1],sq[2],sq[3]}, q1 = {sq[4],sq[5],sq[6],sq[7]};
  *(f32x4*)&red[tg*256 + c0]        = s0;  *(f32x4*)&red[tg*256 + c0 + 4]        = s1;
  *(f32x4*)&red[4096 + tg*256 + c0] = q0;  *(f32x4*)&red[4096 + tg*256 + c0 + 4] = q1;
  __syncthreads();
  if (t < 256){
    float ss = 0.f, qq = 0.f;
    #pragma unroll
    for (int gg = 0; gg < 16; gg++){
      ss += red[gg*256 + t];
      qq += red[4096 + gg*256 + t];
    }
    atomicAdd(&bnS[nc0 + t], ss);
    atomicAdd(&bnQ[nc0 + t], qq);
  }
}

// ---------------------------------------------------------------------------
// finalize: y[b][l][c] bf16 -> out[b][c][l] fp32, BN affine + relu
__global__ __launch_bounds__(256) void k_bn_finalize(
    const unsigned short* __restrict__ y, const float* __restrict__ bnS,
    const float* __restrict__ bnQ, const float* __restrict__ bnw,
    const float* __restrict__ bnb, float* __restrict__ out)
{
  __shared__ float tile[64][65];
  __shared__ float scale_s[64], shift_s[64];
  const int lt = blockIdx.x, ct = blockIdx.y, b = blockIdx.z;
  const int t = threadIdx.x;
  if (t < 64){
    int c = ct*64 + t;
    float s = bnS[c], q = bnQ[c];
    float mean = s * (1.0f / 32768.0f);
    float var  = q * (1.0f / 32768.0f) - mean * mean;
    float inv  = rsqrtf(var + 1e-5f);
    float scv  = bnw[c] * inv;
    scale_s[t] = scv;
    shift_s[t] = bnb[c] - mean * scv;
  }
  const int rr = t >> 3, c8 = (t & 7) * 8;
  #pragma unroll
  for (int pass = 0; pass < 2; pass++){
    int l = rr + pass * 32;
    bf16x8 v = *(const bf16x8*)(y + ((size_t)b * 4096 + lt*64 + l) * 512 + ct*64 + c8);
    #pragma unroll
    for (int s = 0; s < 8; s++) tile[l][c8+s] = bf2f((unsigned short)v[s]);
  }
  __syncthreads();
  #pragma unroll
  for (int pass = 0; pass < 2; pass++){
    int c = rr + pass * 32;
    float scv = scale_s[c], sh = shift_s[c];
    f32x4 o0, o1;
    #pragma unroll
    for (int s = 0; s < 4; s++){
      float v = tile[c8+s][c] * scv + sh;     o0[s] = v > 0.f ? v : 0.f;
      float w = tile[c8+4+s][c] * scv + sh;   o1[s] = w > 0.f ? w : 0.f;
    }
    float* dp = out + ((size_t)b * 512 + ct*64 + c) * 4096 + lt*64 + c8;
    *(f32x4*)dp = o0;
    *(f32x4*)(dp + 4) = o1;
  }
}

// ---------------------------------------------------------------------------
extern "C" void kernel_launch(void* const* d_in, const int* in_sizes, int n_in,
                              void* d_out, int out_size, void* d_ws, size_t ws_size,
                              hipStream_t stream)
{
  const float* x    = (const float*)d_in[0];
  const float* pos  = (const float*)d_in[1];
  const float* Wq   = (const float*)d_in[2];
  const float* bq   = (const float*)d_in[3];
  const float* Wk   = (const float*)d_in[4];
  const float* bk   = (const float*)d_in[5];
  const float* Wv   = (const float*)d_in[6];
  const float* bv   = (const float*)d_in[7];
  const float* Wq1  = (const float*)d_in[8];
  const float* bq1  = (const float*)d_in[9];
  const float* Wk1  = (const float*)d_in[10];
  const float* bk1  = (const float*)d_in[11];
  const float* gam  = (const float*)d_in[12];
  const float* bnw  = (const float*)d_in[13];
  const float* bnb  = (const float*)d_in[14];
  float* out = (float*)d_out;
  char* ws = (char*)d_ws;

  const size_t MB = 1ull << 20;
  const size_t OFF_XSB  = 0;                  // 32MB xs_bf -> y in-place
  const size_t OFF_QB   = 32*MB;              // 32MB Q
  const size_t OFF_XST  = 64*MB;              // 32MB xs^T [8][512][4096]
  const size_t OFF_GP0  = 96*MB;              // 8MB  G part0 fp32
  const size_t OFF_GP1  = 104*MB;             // 8MB  G part1 fp32
  const size_t OFF_GBF  = 112*MB;             // 4MB  G bf16
  const size_t OFF_PBF  = 116*MB;             // 4MB  P bf16
  const size_t OFF_SF   = 120*MB;             // 8MB  S fp32
  const size_t OFF_MIDB = 128*MB;             // 4MB  mid bf16
  const size_t OFF_MIDT = 132*MB;             // 4MB  midT' bf16 (diag-scaled)
  const size_t OFF_WBF  = 136*MB;             // 2.5MB
  const size_t OFF_B5   = 139*MB;             // 10KB
  const size_t OFF_SV   = 140*MB;             // 16KB s
  const size_t OFF_UV   = OFF_SV + 16384;     // 16KB u
  const size_t OFF_WV   = OFF_UV + 16384;     // 16KB w
  const size_t OFF_Z    = 141*MB;             // 128KB fp32
  const size_t OFF_DIAG = 142*MB;
  const size_t OFF_KSUM = OFF_DIAG + 16384;
  const size_t OFF_BNS  = OFF_KSUM + 16384;
  const size_t OFF_BNQ  = OFF_BNS + 2048;
  const size_t WS_NEED  = OFF_BNQ + 2048;
  if (ws_size < WS_NEED) return;

  unsigned short* xsb  = (unsigned short*)(ws + OFF_XSB);
  unsigned short* Qb   = (unsigned short*)(ws + OFF_QB);
  unsigned short* xsT  = (unsigned short*)(ws + OFF_XST);
  float*          Gp0  = (float*)(ws + OFF_GP0);
  float*          Gp1  = (float*)(ws + OFF_GP1);
  unsigned short* Gbf  = (unsigned short*)(ws + OFF_GBF);
  unsigned short* Pbf  = (unsigned short*)(ws + OFF_PBF);
  float*          Sf   = (float*)(ws + OFF_SF);
  unsigned short* midb = (unsigned short*)(ws + OFF_MIDB);
  unsigned short* midT = (unsigned short*)(ws + OFF_MIDT);
  unsigned short* wbf  = (unsigned short*)(ws + OFF_WBF);
  float* bias5 = (float*)(ws + OFF_B5);
  float* svec = (float*)(ws + OFF_SV);
  float* uvec = (float*)(ws + OFF_UV);
  float* wvec = (float*)(ws + OFF_WV);
  float* Zp   = (float*)(ws + OFF_Z);
  float* diag = (float*)(ws + OFF_DIAG);
  float* ksum = (float*)(ws + OFF_KSUM);
  float* bnS  = (float*)(ws + OFF_BNS);
  float* bnQ  = (float*)(ws + OFF_BNQ);

  hipMemsetAsync(ws + OFF_DIAG, 0, 16384 + 16384 + 2048 + 2048, stream);

  k_prep_w  <<<dim3(1024, 5), 256, 0, stream>>>(Wq, Wk, Wv, Wq1, Wk1, wbf);
  k_prep_b  <<<dim3(10),      256, 0, stream>>>(bq, bk, bv, bq1, bk1, bias5);
  k_build_xs<<<dim3(64, 8, 8),256, 0, stream>>>(x, pos, xsb, xsT);

  // fused projections (Q + chained-KV reductions), 2 blocks/CU
  gemm_proj2<<<dim3(2048), 256, 0, stream>>>(xsb, wbf, bias5, Qb, diag, ksum);

  // column sums s, then u = Wq1 s, w = Wk1 s
  k_colsum<<<dim3(8, 8), 256, 0, stream>>>(xsT, svec);
  k_uw    <<<dim3(2, 8), 256, 0, stream>>>(wbf, svec, uvec, wvec);

  // G = xs^T xs (split-K, fp32 partials) -> bf16
  gemm_G    <<<dim3(256),  256, 0, stream>>>(xsT, Gp0, Gp1);
  k_combineG<<<dim3(1024), 256, 0, stream>>>(Gp0, Gp1, Gbf);

  // S = Wq1 G Wk1^T + rank-1 corrections
  gemm_P<<<dim3(128), 256, 0, stream>>>(wbf + 3*262144, Gbf, Pbf);
  gemm_S<<<dim3(128), 256, 0, stream>>>(Pbf, wbf + 4*262144, bias5, uvec, wvec, Sf);

  // Z row-normalizer
  k_z<<<dim3(8192), 256, 0, stream>>>(Qb, ksum, Zp);

  k_softmax<<<dim3(4096), 64, 0, stream>>>(Sf, midb);
  k_transpose_scale<<<dim3(8, 8, 8), 256, 0, stream>>>(midb, diag, midT);

  // result GEMM + residual + BN-stat epilogue (y in-place over xs_bf)
  gemm8_res<<<dim3(256), 512, 0, stream>>>(Qb, midT, Zp, xsb, gam, bnS, bnQ);

  k_bn_finalize<<<dim3(64, 8, 8), 256, 0, stream>>>(xsb, bnS, bnQ, bnw, bnb, out);
}

// Round 8
// 246.065 us; speedup vs baseline: 1.0692x; 1.0692x over previous
//
#include <hip/hip_runtime.h>
#include <stdint.h>

typedef float f32x4 __attribute__((ext_vector_type(4)));
typedef short bf16x8 __attribute__((ext_vector_type(8)));

__device__ __forceinline__ float bf2f(unsigned short h){
  union { unsigned int u; float f; } v; v.u = ((unsigned int)h) << 16; return v.f;
}
__device__ __forceinline__ unsigned short f2bf(float f){
  union { float f; unsigned int u; } v; v.f = f;
  return (unsigned short)((v.u + 0x7fffu + ((v.u >> 16) & 1u)) >> 16);
}

typedef __attribute__((address_space(1))) const unsigned int ga_u32;
typedef __attribute__((address_space(3))) unsigned int ls_u32;
__device__ __forceinline__ void async_load16(const void* g, void* l){
  __builtin_amdgcn_global_load_lds((ga_u32*)g, (ls_u32*)l, 16, 0, 0);
}

#define CFENCE() asm volatile("" ::: "memory")
#define SB0() __builtin_amdgcn_sched_barrier(0)

// ---------------------------------------------------------------------------
__global__ __launch_bounds__(256) void k_prep_w(
    const float* __restrict__ w0, const float* __restrict__ w1,
    const float* __restrict__ w2, const float* __restrict__ w3,
    const float* __restrict__ w4, unsigned short* __restrict__ out)
{
  int i = blockIdx.x * 256 + threadIdx.x;
  const float* w = (blockIdx.y == 0) ? w0 : (blockIdx.y == 1) ? w1 :
                   (blockIdx.y == 2) ? w2 : (blockIdx.y == 3) ? w3 : w4;
  out[(size_t)blockIdx.y * 262144 + i] = f2bf(w[i]);
}
__global__ __launch_bounds__(256) void k_prep_b(
    const float* __restrict__ b0, const float* __restrict__ b1,
    const float* __restrict__ b2, const float* __restrict__ b3,
    const float* __restrict__ b4, float* __restrict__ out)
{
  int i = blockIdx.x * 256 + threadIdx.x;   // 0..2559
  int s = i >> 9, r = i & 511;
  const float* b = (s == 0) ? b0 : (s == 1) ? b1 : (s == 2) ? b2 : (s == 3) ? b3 : b4;
  out[i] = b[r];
}
// wq1x2[e][k] = Wq1bf[e][k % 512], k in [0,1024)
__global__ __launch_bounds__(256) void k_prep_dup(
    const unsigned short* __restrict__ wbf, unsigned short* __restrict__ wq1x2)
{
  const int e = blockIdx.x;
  const int t = threadIdx.x;
  #pragma unroll
  for (int rep = 0; rep < 2; rep++){
    int idx = rep*256 + t;
    unsigned short v = wbf[3*262144 + e*512 + idx];
    wq1x2[(size_t)e*1024 + idx] = v;
    wq1x2[(size_t)e*1024 + 512 + idx] = v;
  }
}

// ---------------------------------------------------------------------------
// build xs_bf[b][l][c], xsT[b][c][l], svec[b][c] partial col-sums.
// pos tile loaded once; loop over all 8 batches. grid (64 lt, 8 ct).
__global__ __launch_bounds__(256) void k_build_xs(
    const float* __restrict__ x, const float* __restrict__ pos,
    unsigned short* __restrict__ xsb, unsigned short* __restrict__ xsT,
    float* __restrict__ svec)
{
  __shared__ float tile[64][65];
  __shared__ unsigned short tile2[64][72];
  __shared__ float sred[256];
  const int lt = blockIdx.x, ct = blockIdx.y;
  const int t = threadIdx.x;
  const int rr = t >> 3, c8 = (t & 7) * 8;
  float pr[16];
  #pragma unroll
  for (int pass = 0; pass < 2; pass++){
    int gl = lt*64 + rr + pass*32;
    f32x4 p0 = *(const f32x4*)(pos + (size_t)gl * 512 + ct*64 + c8);
    f32x4 p1 = *(const f32x4*)(pos + (size_t)gl * 512 + ct*64 + c8 + 4);
    #pragma unroll
    for (int s = 0; s < 4; s++){ pr[pass*8+s] = p0[s]; pr[pass*8+4+s] = p1[s]; }
  }
  for (int b = 0; b < 8; b++){
    #pragma unroll
    for (int pass = 0; pass < 2; pass++){
      int r = rr + pass * 32;
      const float* src = x + ((size_t)b * 512 + ct*64 + r) * 4096 + lt*64 + c8;
      f32x4 v0 = *(const f32x4*)src;
      f32x4 v1 = *(const f32x4*)(src + 4);
      #pragma unroll
      for (int s = 0; s < 4; s++){ tile[r][c8+s] = v0[s]; tile[r][c8+4+s] = v1[s]; }
    }
    __syncthreads();
    #pragma unroll
    for (int pass = 0; pass < 2; pass++){
      int ll = rr + pass * 32;
      int gl = lt*64 + ll;
      bf16x8 hv;
      #pragma unroll
      for (int s = 0; s < 8; s++){
        unsigned short h = f2bf(tile[c8+s][ll] + pr[pass*8+s]);
        hv[s] = (short)h;
        tile2[c8+s][ll] = h;
      }
      *(bf16x8*)(xsb + ((size_t)b * 4096 + gl) * 512 + ct*64 + c8) = hv;
    }
    __syncthreads();
    #pragma unroll
    for (int rep = 0; rep < 2; rep++){
      int c = rep*32 + (t >> 3);
      int l0 = (t & 7) * 8;
      bf16x8 v = *(const bf16x8*)&tile2[c][l0];
      *(bf16x8*)(xsT + ((size_t)b * 512 + ct*64 + c) * 4096 + lt*64 + l0) = v;
    }
    {
      const int c = t & 63, lq = t >> 6;
      float s_ = 0.f;
      #pragma unroll
      for (int j = 0; j < 16; j++) s_ += bf2f(tile2[c][lq*16 + j]);
      sred[t] = s_;
      __syncthreads();
      if (t < 64){
        float ss = sred[t] + sred[t+64] + sred[t+128] + sred[t+192];
        atomicAdd(&svec[b*512 + ct*64 + t], ss);
      }
    }
    __syncthreads();
  }
}

// ---------------------------------------------------------------------------
// u[b][e] = Wq1 . s   (sel 0)    w[b][d] = Wk1 . s  (sel 1)
__global__ __launch_bounds__(256) void k_uw(
    const unsigned short* __restrict__ wbf, const float* __restrict__ svec,
    float* __restrict__ u, float* __restrict__ w)
{
  __shared__ float sv[512];
  const int sel = blockIdx.x, b = blockIdx.y;
  const int t = threadIdx.x;
  sv[t] = svec[b*512 + t]; sv[t+256] = svec[b*512 + t + 256];
  __syncthreads();
  const unsigned short* Wp = wbf + (size_t)(3 + sel) * 262144;
  float* o = sel ? w : u;
  #pragma unroll
  for (int rep = 0; rep < 2; rep++){
    int e = rep*256 + t;
    const unsigned short* row = Wp + (size_t)e * 512;
    float acc = 0.f;
    for (int ch = 0; ch < 64; ch++){
      bf16x8 v = *(const bf16x8*)(row + ch*8);
      #pragma unroll
      for (int j = 0; j < 8; j++) acc += bf2f((unsigned short)v[j]) * sv[ch*8+j];
    }
    o[b*512 + e] = acc;
  }
}

// ---------------------------------------------------------------------------
// Z[row] = 1 / sum_c Q[row,c]*(Ksum[b,c]+eps)
__global__ __launch_bounds__(256) void k_z(
    const unsigned short* __restrict__ Qb, const float* __restrict__ ksum,
    float* __restrict__ Z)
{
  const int row = blockIdx.x * 4 + (threadIdx.x >> 6);
  const int lane = threadIdx.x & 63;
  const int b = row >> 12;
  bf16x8 q = *(const bf16x8*)(Qb + (size_t)row * 512 + lane * 8);
  f32x4 k0 = *(const f32x4*)(ksum + b*512 + lane*8);
  f32x4 k1 = *(const f32x4*)(ksum + b*512 + lane*8 + 4);
  float den = 0.f;
  #pragma unroll
  for (int s = 0; s < 4; s++) den += bf2f((unsigned short)q[s])   * (k0[s] + 1e-6f);
  #pragma unroll
  for (int s = 0; s < 4; s++) den += bf2f((unsigned short)q[4+s]) * (k1[s] + 1e-6f);
  #pragma unroll
  for (int m = 1; m < 64; m <<= 1) den += __shfl_xor(den, m);
  if (lane == 0) Z[row] = 1.0f / den;
}

// ---------------------------------------------------------------------------
// row softmax: S[row][0..511] fp32 -> mid bf16
__global__ __launch_bounds__(64) void k_softmax(
    const float* __restrict__ S, unsigned short* __restrict__ mid)
{
  const size_t row = blockIdx.x;
  const int lane = threadIdx.x;
  const float* p = S + row * 512 + lane * 8;
  f32x4 v0 = *(const f32x4*)p, v1 = *(const f32x4*)(p + 4);
  float mx = v0[0];
  #pragma unroll
  for (int s = 1; s < 4; s++) mx = fmaxf(mx, v0[s]);
  #pragma unroll
  for (int s = 0; s < 4; s++) mx = fmaxf(mx, v1[s]);
  #pragma unroll
  for (int m = 1; m < 64; m <<= 1) mx = fmaxf(mx, __shfl_xor(mx, m));
  float e[8]; float sum = 0.f;
  #pragma unroll
  for (int s = 0; s < 4; s++){ e[s]   = __expf(v0[s] - mx); sum += e[s]; }
  #pragma unroll
  for (int s = 0; s < 4; s++){ e[4+s] = __expf(v1[s] - mx); sum += e[4+s]; }
  #pragma unroll
  for (int m = 1; m < 64; m <<= 1) sum += __shfl_xor(sum, m);
  float inv = 1.0f / sum;
  bf16x8 hv;
  #pragma unroll
  for (int s = 0; s < 8; s++) hv[s] = (short)f2bf(e[s] * inv);
  *(bf16x8*)(mid + row * 512 + lane * 8) = hv;
}

// ---------------------------------------------------------------------------
// mid transpose with diag fold: midT[z][d][c] = mid[z][c][d] * diag[z][c]
__global__ __launch_bounds__(256) void k_transpose_scale(
    const unsigned short* __restrict__ in, const float* __restrict__ diag,
    unsigned short* __restrict__ out)
{
  __shared__ float tile[64][65];
  const int rt = blockIdx.x, ct = blockIdx.y, z = blockIdx.z;
  const unsigned short* src = in  + (size_t)z * 262144;
  unsigned short*       dst = out + (size_t)z * 262144;
  const int t = threadIdx.x;
  const int rr = t >> 3, c8 = (t & 7) * 8;
  #pragma unroll
  for (int pass = 0; pass < 2; pass++){
    int r = rr + pass * 32;
    bf16x8 v = *(const bf16x8*)(src + (size_t)(rt*64 + r) * 512 + ct*64 + c8);
    #pragma unroll
    for (int s = 0; s < 8; s++) tile[r][c8+s] = bf2f((unsigned short)v[s]);
  }
  __syncthreads();
  f32x4 dg0 = *(const f32x4*)(diag + z*512 + rt*64 + c8);
  f32x4 dg1 = *(const f32x4*)(diag + z*512 + rt*64 + c8 + 4);
  #pragma unroll
  for (int pass = 0; pass < 2; pass++){
    int c = rr + pass * 32;
    bf16x8 hv;
    #pragma unroll
    for (int s = 0; s < 4; s++) hv[s]   = (short)f2bf(tile[c8+s][c]   * dg0[s]);
    #pragma unroll
    for (int s = 0; s < 4; s++) hv[4+s] = (short)f2bf(tile[c8+4+s][c] * dg1[s]);
    *(bf16x8*)(dst + (size_t)(ct*64 + c) * 512 + rt*64 + c8) = hv;
  }
}

// ===========================================================================
// 128x128-tile 2-phase GEMM machinery (64KB LDS -> 2 blocks/CU).
// ===========================================================================
#define GEMM_PRE()                                                            \
  const int tid = threadIdx.x;                                                \
  const int lane = tid & 63;                                                  \
  const int wave = tid >> 6;                                                  \
  const int wm = wave >> 1, wn = wave & 1;                                    \
  size_t aoff[4], boff[4]; int ldsq[4];                                       \
  _Pragma("unroll")                                                           \
  for (int i = 0; i < 4; i++){                                                \
    int qq = i*4 + wave;                                                      \
    int ch = qq*64 + lane;                                                    \
    int m  = ch >> 3, p = ch & 7;                                             \
    int lc = p ^ (m & 7);                                                     \
    aoff[i] = (size_t)(m0 + m) * K + lc*8;                                    \
    boff[i] = (size_t)m * K + lc*8;                                           \
    ldsq[i] = qq * 1024;                                                      \
  }                                                                           \
  f32x4 acc[4][4];                                                            \
  const f32x4 vzero = {0.f,0.f,0.f,0.f};                                      \
  _Pragma("unroll")                                                           \
  for (int i = 0; i < 4; i++)                                                 \
    _Pragma("unroll")                                                         \
    for (int j = 0; j < 4; j++) acc[i][j] = vzero;                            \
  int arow[4], brow[4];                                                       \
  _Pragma("unroll")                                                           \
  for (int f = 0; f < 4; f++){                                                \
    arow[f] = (wm*64 + f*16 + (lane & 15)) * 64;                              \
    brow[f] = (wn*64 + f*16 + (lane & 15)) * 64;                              \
  }                                                                           \
  const int kg = lane >> 4;                                                   \
  const int l7 = lane & 7;                                                    \
  const int l15 = lane & 15;

#define GEMM_STAGE2(buf, kt, BB)                                              \
  _Pragma("unroll")                                                           \
  for (int i = 0; i < 4; i++){                                                \
    async_load16(Ae + aoff[i] + (kt)*64, (char*)&smem[(buf)*8192] + ldsq[i]); \
    async_load16((BB) + boff[i] + (kt)*64, (char*)&smem[16384 + (buf)*8192] + ldsq[i]); \
  }

#define GEMM_COMPUTE2(buf, ACC)                                               \
  _Pragma("unroll")                                                           \
  for (int ks = 0; ks < 2; ks++){                                             \
    bf16x8 a[4], b[4];                                                        \
    const int pa = (ks*4 + kg) ^ l7;                                          \
    _Pragma("unroll")                                                         \
    for (int f = 0; f < 4; f++){                                              \
      a[f] = *(const bf16x8*)&smem[(buf)*8192 + arow[f] + pa*8];              \
      b[f] = *(const bf16x8*)&smem[16384 + (buf)*8192 + brow[f] + pa*8];      \
    }                                                                         \
    _Pragma("unroll")                                                         \
    for (int i = 0; i < 4; i++)                                               \
      _Pragma("unroll")                                                       \
      for (int j = 0; j < 4; j++)                                             \
        (ACC)[i][j] = __builtin_amdgcn_mfma_f32_16x16x32_bf16(a[i], b[j], (ACC)[i][j], 0, 0, 0); \
  }

#define GEMM_KLOOP2(nkt, BB)                                                  \
  GEMM_STAGE2(0, 0, BB);                                                      \
  __syncthreads();                                                            \
  { int cur = 0;                                                              \
    for (int kt = 0; kt < (nkt); kt++){                                       \
      if (kt + 1 < (nkt)) { GEMM_STAGE2(cur ^ 1, kt + 1, BB); }               \
      GEMM_COMPUTE2(cur, acc);                                                \
      __syncthreads();                                                        \
      cur ^= 1;                                                               \
    } }

// ---------------------------------------------------------------------------
// G syrk split-K, bf16 stacked: Gstack[z][c1][part*512+c2] (partials symmetric)
__global__ __launch_bounds__(256) void gemm_G(
    const unsigned short* __restrict__ A,
    unsigned short* __restrict__ Gstk)
{
  __shared__ unsigned short smem[32768];
  const int bid = blockIdx.x;
  const int wgid = (bid & 7) * 32 + (bid >> 3);    // 256 blocks
  const int part = wgid & 1;
  const int ntile = (wgid >> 1) & 3;
  const int mtile = (wgid >> 3) & 3;
  const int z = wgid >> 5;
  const int m0 = mtile * 128, n0 = ntile * 128;
  const int K = 4096;
  const unsigned short* Ae = A + (size_t)z * 2097152 + part * 2048;
  const unsigned short* Be = Ae + (size_t)n0 * 4096;

  GEMM_PRE();
  GEMM_KLOOP2(32, Be);

  #pragma unroll
  for (int j = 0; j < 4; j++){
    const int cl = wn*64 + j*16 + l15;
    #pragma unroll
    for (int i = 0; i < 4; i++){
      const int rb = wm*64 + i*16 + kg*4;
      #pragma unroll
      for (int q = 0; q < 4; q++)
        smem[(rb + q)*136 + cl] = f2bf(acc[i][j][q]);
    }
  }
  __syncthreads();
  #pragma unroll
  for (int rep = 0; rep < 8; rep++){
    const int rl = rep*16 + (tid >> 4);
    const int c0 = (tid & 15) * 8;
    bf16x8 v = *(const bf16x8*)&smem[rl*136 + c0];
    *(bf16x8*)(Gstk + (size_t)z*524288 + (size_t)(m0 + rl)*1024 + part*512 + n0 + c0) = v;
  }
}

// ---------------------------------------------------------------------------
// P[z] = Wq1 @ (G0+G1) via stacked K=1024 (A = wq1x2, Bt = Gstack rows)
__global__ __launch_bounds__(256) void gemm_P(
    const unsigned short* __restrict__ Wq1x2,
    const unsigned short* __restrict__ Gstk,
    unsigned short* __restrict__ P)
{
  __shared__ unsigned short smem[32768];
  const int bid = blockIdx.x;
  const int wgid = (bid & 7) * 16 + (bid >> 3);    // 128 blocks
  const int z = wgid >> 4;
  const int mtile = (wgid >> 2) & 3, ntile = wgid & 3;
  const int m0 = mtile * 128, n0 = ntile * 128;
  const int K = 1024;
  const unsigned short* Ae = Wq1x2;
  const unsigned short* Be = Gstk + (size_t)z * 524288 + (size_t)n0 * 1024;

  GEMM_PRE();
  GEMM_KLOOP2(16, Be);

  #pragma unroll
  for (int j = 0; j < 4; j++){
    const int cl = wn*64 + j*16 + l15;
    #pragma unroll
    for (int i = 0; i < 4; i++){
      const int rb = wm*64 + i*16 + kg*4;
      #pragma unroll
      for (int q = 0; q < 4; q++)
        smem[(rb + q)*136 + cl] = f2bf(acc[i][j][q]);
    }
  }
  __syncthreads();
  #pragma unroll
  for (int rep = 0; rep < 8; rep++){
    const int rl = rep*16 + (tid >> 4);
    const int c0 = (tid & 15) * 8;
    bf16x8 v = *(const bf16x8*)&smem[rl*136 + c0];
    *(bf16x8*)(P + (size_t)z * 262144 + (size_t)(m0 + rl) * 512 + n0 + c0) = v;
  }
}

// ---------------------------------------------------------------------------
// S[z] = P[z] @ Wk1^T + u bk1^T + bq1 w^T + L bq1 bk1^T  (fp32 out)
__global__ __launch_bounds__(256) void gemm_S(
    const unsigned short* __restrict__ P,
    const unsigned short* __restrict__ Wk1b,
    const float* __restrict__ bias5,
    const float* __restrict__ u, const float* __restrict__ w,
    float* __restrict__ Sf)
{
  __shared__ unsigned short smem[32768];
  const int bid = blockIdx.x;
  const int wgid = (bid & 7) * 16 + (bid >> 3);    // 128 blocks
  const int z = wgid >> 4;
  const int mtile = (wgid >> 2) & 3, ntile = wgid & 3;
  const int m0 = mtile * 128, n0 = ntile * 128;
  const int K = 512;
  const unsigned short* Ae = P + (size_t)z * 262144;
  const unsigned short* Be = Wk1b + (size_t)n0 * 512;

  GEMM_PRE();
  GEMM_KLOOP2(8, Be);

  #pragma unroll
  for (int j = 0; j < 4; j++){
    int cd = n0 + wn*64 + j*16 + l15;
    float bkv = bias5[2048 + cd];
    float wv  = w[z*512 + cd] + 4096.0f * bkv;
    #pragma unroll
    for (int i = 0; i < 4; i++){
      int r = m0 + wm*64 + i*16 + kg*4;
      #pragma unroll
      for (int q = 0; q < 4; q++){
        int rr = r + q;
        float uq  = u[z*512 + rr];
        float bqv = bias5[1536 + rr];
        Sf[(size_t)z * 262144 + (size_t)rr * 512 + cd] =
            acc[i][j][q] + uq * bkv + bqv * wv;
      }
    }
  }
}

// ---------------------------------------------------------------------------
// fused projections, 128² tiles, 2 blocks/CU. grid = 2048.
__global__ __launch_bounds__(256, 2) void gemm_proj2(
    const unsigned short* __restrict__ A,
    const unsigned short* __restrict__ W,
    const float* __restrict__ bias5,
    unsigned short* __restrict__ Qb,
    float* __restrict__ diag, float* __restrict__ ksum)
{
  __shared__ unsigned short smem[32768];   // 64KB
  const int bid = blockIdx.x;
  const int wgid = (bid & 7) * 256 + (bid >> 3);   // 2048 % 8 == 0: bijective
  const int mtile = wgid >> 3;                     // 0..255
  const int unit  = wgid & 7;
  const int m0 = mtile * 128;
  const int K = 512;
  const unsigned short* Ae = A;

  int mode, cb;
  const unsigned short* BeK; const unsigned short* BeV = W;
  if (unit < 4){ mode = 0; cb = unit*128;     BeK = W + (size_t)cb * 512; }
  else         { mode = 1; cb = (unit-4)*128; BeK = W + 262144 + (size_t)cb * 512;
                                              BeV = W + 524288 + (size_t)cb * 512; }

  GEMM_PRE();

  if (mode == 1){
    const int bz = mtile >> 5;
    GEMM_STAGE2(0, 0, BeK);
    __syncthreads();
    int cur = 0;
    for (int kt = 0; kt < 8; kt++){
      if (kt < 7) { GEMM_STAGE2(cur ^ 1, kt + 1, BeK); }
      else        { GEMM_STAGE2(cur ^ 1, 0, BeV); }
      GEMM_COMPUTE2(cur, acc);
      __syncthreads();
      cur ^= 1;
    }
    GEMM_STAGE2(cur ^ 1, 1, BeV);
    unsigned int kpk[4][4][2];
    #pragma unroll
    for (int j = 0; j < 4; j++){
      const int cj = cb + wn*64 + j*16 + l15;
      const float bb = bias5[512 + cj];
      float ks_ = 0.f;
      #pragma unroll
      for (int i = 0; i < 4; i++){
        #pragma unroll
        for (int h = 0; h < 2; h++){
          float v0 = acc[i][j][2*h]   + bb; v0 = v0 > 0.f ? v0 : 0.f;
          float v1 = acc[i][j][2*h+1] + bb; v1 = v1 > 0.f ? v1 : 0.f;
          unsigned short h0 = f2bf(v0), h1 = f2bf(v1);
          kpk[i][j][h] = (unsigned)h0 | ((unsigned)h1 << 16);
          ks_ += bf2f(h0) + bf2f(h1);
        }
        acc[i][j] = vzero;
      }
      ks_ += __shfl_xor(ks_, 16);
      ks_ += __shfl_xor(ks_, 32);
      if (lane < 16) atomicAdd(&ksum[bz*512 + cj], ks_);
    }
    for (int kt = 0; kt < 8; kt++){
      if (kt >= 1 && kt < 7) { GEMM_STAGE2(cur ^ 1, kt + 1, BeV); }
      GEMM_COMPUTE2(cur, acc);
      __syncthreads();
      cur ^= 1;
    }
    #pragma unroll
    for (int j = 0; j < 4; j++){
      const int cj = cb + wn*64 + j*16 + l15;
      const float bb = bias5[1024 + cj];
      float dv = 0.f;
      #pragma unroll
      for (int i = 0; i < 4; i++){
        #pragma unroll
        for (int h = 0; h < 2; h++){
          float v0 = bf2f(f2bf(acc[i][j][2*h]   + bb));
          float v1 = bf2f(f2bf(acc[i][j][2*h+1] + bb));
          dv += bf2f((unsigned short)(kpk[i][j][h] & 0xffffu)) * v0
              + bf2f((unsigned short)(kpk[i][j][h] >> 16))     * v1;
        }
      }
      dv += __shfl_xor(dv, 16);
      dv += __shfl_xor(dv, 32);
      if (lane < 16) atomicAdd(&diag[bz*512 + cj], dv);
    }
    return;
  }

  GEMM_KLOOP2(8, BeK);

  #pragma unroll
  for (int j = 0; j < 4; j++){
    const int cl = wn*64 + j*16 + l15;
    const float bb = bias5[cb + cl];
    #pragma unroll
    for (int i = 0; i < 4; i++){
      const int rb = wm*64 + i*16 + kg*4;
      #pragma unroll
      for (int q = 0; q < 4; q++){
        float v = acc[i][j][q] + bb; v = v > 0.f ? v : 0.f;
        smem[(rb + q)*136 + cl] = f2bf(v);
      }
    }
  }
  __syncthreads();
  #pragma unroll
  for (int rep = 0; rep < 8; rep++){
    const int rl = rep*16 + (tid >> 4);
    const int c0 = (tid & 15) * 8;
    bf16x8 v = *(const bf16x8*)&smem[rl*136 + c0];
    *(bf16x8*)(Qb + (size_t)(m0 + rl) * 512 + cb + c0) = v;
  }
}

// ===========================================================================
// 256x256-tile, 8-wave, 8-phase counted-vmcnt GEMM (result GEMM only).
// ===========================================================================
#define G8_PRE(AE)                                                            \
  const int t = threadIdx.x;                                                  \
  const int lane = t & 63;                                                    \
  const int wave = t >> 6;                                                    \
  const int wm = wave >> 2, wn = wave & 3;                                    \
  const int l15 = lane & 15, kg = lane >> 4;                                  \
  const int lcw = ((t & 7) ^ ((t >> 3) & 7)) * 8;                             \
  const unsigned short* a_src = (AE) + (size_t)(m0 + (t >> 3)) * 512 + lcw;   \
  f32x4 acc[8][4];                                                            \
  const f32x4 vzero = {0.f,0.f,0.f,0.f};                                      \
  _Pragma("unroll")                                                           \
  for (int i = 0; i < 8; i++)                                                 \
    _Pragma("unroll")                                                         \
    for (int j = 0; j < 4; j++) acc[i][j] = vzero;                            \
  bf16x8 af[4][2], bf[4][2];

#define STAGE_A(D,H,TT) do{                                                   \
  async_load16(a_src + (H)*65536 + (TT)*64,                                   \
               (char*)smem + ((D)*16384 + (H)*8192 + t*8)*2);                 \
  async_load16(a_src + (H)*65536 + 32768 + (TT)*64,                           \
               (char*)smem + ((D)*16384 + (H)*8192 + 4096 + t*8)*2);          \
}while(0)

#define STAGE_B(D,H,TT) do{                                                   \
  async_load16(b_src + (H)*65536 + (TT)*64,                                   \
               (char*)smem + (32768 + (D)*16384 + (H)*8192 + t*8)*2);         \
  async_load16(b_src + (H)*65536 + 32768 + (TT)*64,                           \
               (char*)smem + (32768 + (D)*16384 + (H)*8192 + 4096 + t*8)*2);  \
}while(0)

#define READ_A(D, MH) do{                                                     \
  _Pragma("unroll")                                                           \
  for (int mfl = 0; mfl < 4; ++mfl){                                          \
    const int rl = ((MH)*4 + mfl)*16 + l15;                                   \
    _Pragma("unroll")                                                         \
    for (int ks = 0; ks < 2; ++ks){                                           \
      const int ck = (ks*4 + kg) ^ (rl & 7);                                  \
      af[mfl][ks] = *(const bf16x8*)&smem[(D)*16384 + wm*8192 + rl*64 + ck*8];\
    }                                                                         \
  }                                                                           \
}while(0)

#define READ_B(D, NP) do{                                                     \
  _Pragma("unroll")                                                           \
  for (int nfl = 0; nfl < 2; ++nfl){                                          \
    const int nf = (NP)*2 + nfl;                                              \
    const int rbl = (wn & 1)*64 + nf*16 + l15;                                \
    _Pragma("unroll")                                                         \
    for (int ks = 0; ks < 2; ++ks){                                           \
      const int ck = (ks*4 + kg) ^ (rbl & 7);                                 \
      bf[nf][ks] = *(const bf16x8*)&smem[32768 + (D)*16384 + (wn>>1)*8192 + rbl*64 + ck*8]; \
    }                                                                         \
  }                                                                           \
}while(0)

#define QUAD(MH, NP)                                                          \
  _Pragma("unroll")                                                           \
  for (int mfl = 0; mfl < 4; ++mfl)                                           \
    _Pragma("unroll")                                                         \
    for (int nfl = 0; nfl < 2; ++nfl)                                         \
      _Pragma("unroll")                                                       \
      for (int ks = 0; ks < 2; ++ks)                                          \
        acc[(MH)*4+mfl][(NP)*2+nfl] = __builtin_amdgcn_mfma_f32_16x16x32_bf16(\
            af[mfl][ks], bf[(NP)*2+nfl][ks], acc[(MH)*4+mfl][(NP)*2+nfl], 0,0,0);

#define PH_MID()  CFENCE(); __builtin_amdgcn_s_barrier();                     \
  __builtin_amdgcn_s_setprio(1); SB0()
#define PH_END()  SB0(); __builtin_amdgcn_s_setprio(0); CFENCE();             \
  __builtin_amdgcn_s_barrier(); CFENCE()
#define PH_END_VM4() SB0(); __builtin_amdgcn_s_setprio(0);                    \
  asm volatile("s_waitcnt vmcnt(4)" ::: "memory");                            \
  __builtin_amdgcn_s_barrier(); CFENCE()
#define PH_END_VM0() SB0(); __builtin_amdgcn_s_setprio(0);                    \
  asm volatile("s_waitcnt vmcnt(0)" ::: "memory");                            \
  __builtin_amdgcn_s_barrier(); CFENCE()

#define G8_KLOOP()                                                            \
  STAGE_A(0,0,0); STAGE_A(0,1,0); STAGE_B(0,0,0); STAGE_B(0,1,0);             \
  STAGE_B(1,0,1); STAGE_B(1,1,1);                                             \
  asm volatile("s_waitcnt vmcnt(4)" ::: "memory");                            \
  __builtin_amdgcn_s_barrier(); CFENCE();                                     \
  for (int it = 0; it < 3; ++it){                                             \
    const int t1 = 2*it + 1, t2 = 2*it + 2, t3 = 2*it + 3;                    \
    READ_A(0,0); READ_B(0,0); STAGE_A(1,0,t1);                                \
    PH_MID(); QUAD(0,0); PH_END();                                            \
    READ_B(0,1); STAGE_A(1,1,t1);                                             \
    PH_MID(); QUAD(0,1); PH_END();                                            \
    READ_A(0,1); STAGE_B(0,0,t2);                                             \
    PH_MID(); QUAD(1,0); PH_END();                                            \
    STAGE_A(0,0,t2);                                                          \
    PH_MID(); QUAD(1,1); PH_END_VM4();                                        \
    READ_A(1,0); READ_B(1,0); STAGE_A(0,1,t2);                                \
    PH_MID(); QUAD(0,0); PH_END();                                            \
    READ_B(1,1); STAGE_B(0,1,t2);                                             \
    PH_MID(); QUAD(0,1); PH_END();                                            \
    READ_A(1,1); STAGE_B(1,0,t3);                                             \
    PH_MID(); QUAD(1,0); PH_END();                                            \
    STAGE_B(1,1,t3);                                                          \
    PH_MID(); QUAD(1,1); PH_END_VM4();                                        \
  }                                                                           \
  { READ_A(0,0); READ_B(0,0); STAGE_A(1,0,7);                                 \
    PH_MID(); QUAD(0,0); PH_END();                                            \
    READ_B(0,1); STAGE_A(1,1,7);                                              \
    PH_MID(); QUAD(0,1); PH_END();                                            \
    READ_A(0,1);                                                              \
    PH_MID(); QUAD(1,0); PH_END();                                            \
    PH_MID(); QUAD(1,1); PH_END_VM0();                                        \
    READ_A(1,0); READ_B(1,0);                                                 \
    PH_MID(); QUAD(0,0); PH_END();                                            \
    READ_B(1,1);                                                              \
    PH_MID(); QUAD(0,1); PH_END();                                            \
    READ_A(1,1);                                                              \
    PH_MID(); QUAD(1,0); PH_END();                                            \
    PH_MID(); QUAD(1,1); PH_END(); }

// ---------------------------------------------------------------------------
// result GEMM: y = xs + gamma*Z[l]*(Q @ midT'^T) in-place + BN stats.
__global__ __launch_bounds__(512, 2) void gemm8_res(
    const unsigned short* __restrict__ A,
    const unsigned short* __restrict__ Bt,
    const float* __restrict__ Zp,
    unsigned short* __restrict__ outh,
    const float* __restrict__ gamma_p,
    float* __restrict__ bnS, float* __restrict__ bnQ)
{
  __shared__ unsigned short smem[65536];
  __shared__ float zbuf[256];
  const int bid = blockIdx.x;
  const int wgid = (bid & 7) * 32 + (bid >> 3);   // 256 % 8 == 0
  const int mtile = wgid >> 1;
  const int ntile = wgid & 1;
  const int m0 = mtile * 256;
  const int nc0 = ntile * 256;

  G8_PRE(A);
  const unsigned short* b_src =
      Bt + (size_t)(mtile >> 4) * 262144 + (size_t)(nc0 + (t >> 3)) * 512 + lcw;

  G8_KLOOP();

  const float g = gamma_p[0];
  __syncthreads();
  if (t < 256) zbuf[t] = Zp[m0 + t];
  __syncthreads();
  #pragma unroll
  for (int nf = 0; nf < 4; nf++){
    int cl = wn*64 + nf*16 + l15;
    #pragma unroll
    for (int mf = 0; mf < 8; mf++){
      int rbase = wm*128 + mf*16 + kg*4;
      #pragma unroll
      for (int q = 0; q < 4; q++){
        int rl = rbase + q;
        smem[rl*256 + (cl ^ (((rl >> 2) & 3) << 4))] =
            f2bf(g * zbuf[rl] * acc[mf][nf][q]);
      }
    }
  }
  __syncthreads();
  float sc[8] = {0.f,0.f,0.f,0.f,0.f,0.f,0.f,0.f};
  float sq[8] = {0.f,0.f,0.f,0.f,0.f,0.f,0.f,0.f};
  const int c0 = (t & 31) * 8;
  #pragma unroll
  for (int rep = 0; rep < 16; rep++){
    int rl = rep*16 + (t >> 5);
    bf16x8 ga = *(const bf16x8*)&smem[rl*256 + (c0 ^ (((rl >> 2) & 3) << 4))];
    size_t gidx = (size_t)(m0 + rl) * 512 + nc0 + c0;
    bf16x8 xv = *(const bf16x8*)(outh + gidx);
    bf16x8 yv;
    #pragma unroll
    for (int j = 0; j < 8; j++){
      float y = bf2f((unsigned short)xv[j]) + bf2f((unsigned short)ga[j]);
      yv[j] = (short)f2bf(y);
      sc[j] += y; sq[j] += y * y;
    }
    *(bf16x8*)(outh + gidx) = yv;
  }
  __syncthreads();
  float* red = (float*)(void*)smem;
  const int tg = t >> 5;
  f32x4 s0 = {sc[0],sc[1],sc[2],sc[3]}, s1 = {sc[4],sc[5],sc[6],sc[7]};
  f32x4 q0 = {sq[0],sq[1],sq[2],sq[3]}, q1 = {sq[4],sq[5],sq[6],sq[7]};
  *(f32x4*)&red[tg*256 + c0]        = s0;  *(f32x4*)&red[tg*256 + c0 + 4]        = s1;
  *(f32x4*)&red[4096 + tg*256 + c0] = q0;  *(f32x4*)&red[4096 + tg*256 + c0 + 4] = q1;
  __syncthreads();
  if (t < 256){
    float ss = 0.f, qq = 0.f;
    #pragma unroll
    for (int gg = 0; gg < 16; gg++){
      ss += red[gg*256 + t];
      qq += red[4096 + gg*256 + t];
    }
    atomicAdd(&bnS[nc0 + t], ss);
    atomicAdd(&bnQ[nc0 + t], qq);
  }
}

// ---------------------------------------------------------------------------
// finalize: y[b][l][c] bf16 -> out[b][c][l] fp32, BN affine + relu
__global__ __launch_bounds__(256) void k_bn_finalize(
    const unsigned short* __restrict__ y, const float* __restrict__ bnS,
    const float* __restrict__ bnQ, const float* __restrict__ bnw,
    const float* __restrict__ bnb, float* __restrict__ out)
{
  __shared__ float tile[64][65];
  __shared__ float scale_s[64], shift_s[64];
  const int lt = blockIdx.x, ct = blockIdx.y, b = blockIdx.z;
  const int t = threadIdx.x;
  if (t < 64){
    int c = ct*64 + t;
    float s = bnS[c], q = bnQ[c];
    float mean = s * (1.0f / 32768.0f);
    float var  = q * (1.0f / 32768.0f) - mean * mean;
    float inv  = rsqrtf(var + 1e-5f);
    float scv  = bnw[c] * inv;
    scale_s[t] = scv;
    shift_s[t] = bnb[c] - mean * scv;
  }
  const int rr = t >> 3, c8 = (t & 7) * 8;
  #pragma unroll
  for (int pass = 0; pass < 2; pass++){
    int l = rr + pass * 32;
    bf16x8 v = *(const bf16x8*)(y + ((size_t)b * 4096 + lt*64 + l) * 512 + ct*64 + c8);
    #pragma unroll
    for (int s = 0; s < 8; s++) tile[l][c8+s] = bf2f((unsigned short)v[s]);
  }
  __syncthreads();
  #pragma unroll
  for (int pass = 0; pass < 2; pass++){
    int c = rr + pass * 32;
    float scv = scale_s[c], sh = shift_s[c];
    f32x4 o0, o1;
    #pragma unroll
    for (int s = 0; s < 4; s++){
      float v = tile[c8+s][c] * scv + sh;     o0[s] = v > 0.f ? v : 0.f;
      float w = tile[c8+4+s][c] * scv + sh;   o1[s] = w > 0.f ? w : 0.f;
    }
    float* dp = out + ((size_t)b * 512 + ct*64 + c) * 4096 + lt*64 + c8;
    *(f32x4*)dp = o0;
    *(f32x4*)(dp + 4) = o1;
  }
}

// ---------------------------------------------------------------------------
extern "C" void kernel_launch(void* const* d_in, const int* in_sizes, int n_in,
                              void* d_out, int out_size, void* d_ws, size_t ws_size,
                              hipStream_t stream)
{
  const float* x    = (const float*)d_in[0];
  const float* pos  = (const float*)d_in[1];
  const float* Wq   = (const float*)d_in[2];
  const float* bq   = (const float*)d_in[3];
  const float* Wk   = (const float*)d_in[4];
  const float* bk   = (const float*)d_in[5];
  const float* Wv   = (const float*)d_in[6];
  const float* bv   = (const float*)d_in[7];
  const float* Wq1  = (const float*)d_in[8];
  const float* bq1  = (const float*)d_in[9];
  const float* Wk1  = (const float*)d_in[10];
  const float* bk1  = (const float*)d_in[11];
  const float* gam  = (const float*)d_in[12];
  const float* bnw  = (const float*)d_in[13];
  const float* bnb  = (const float*)d_in[14];
  float* out = (float*)d_out;
  char* ws = (char*)d_ws;

  const size_t MB = 1ull << 20;
  const size_t OFF_XSB  = 0;                  // 32MB xs_bf -> y in-place
  const size_t OFF_QB   = 32*MB;              // 32MB Q
  const size_t OFF_XST  = 64*MB;              // 32MB xs^T [8][512][4096]
  const size_t OFF_GSTK = 96*MB;              // 8MB  Gstack bf16 [8][512][1024]
  const size_t OFF_PBF  = 104*MB;             // 4MB  P bf16
  const size_t OFF_SF   = 108*MB;             // 8MB  S fp32
  const size_t OFF_MIDB = 116*MB;             // 4MB  mid bf16
  const size_t OFF_MIDT = 120*MB;             // 4MB  midT' bf16 (diag-scaled)
  const size_t OFF_WBF  = 124*MB;             // 2.5MB
  const size_t OFF_WQ2  = 127*MB;             // 1MB  Wq1 duplicated [512][1024]
  const size_t OFF_B5   = 128*MB + 512*1024;  // 10KB
  const size_t OFF_UV   = 129*MB;             // 16KB u
  const size_t OFF_WV   = OFF_UV + 16384;     // 16KB w
  const size_t OFF_Z    = OFF_WV + 16384;     // 128KB Z fp32
  const size_t OFF_DIAG = 130*MB;             // zeroed region start
  const size_t OFF_KSUM = OFF_DIAG + 16384;
  const size_t OFF_BNS  = OFF_KSUM + 16384;
  const size_t OFF_BNQ  = OFF_BNS + 2048;
  const size_t OFF_SV   = OFF_BNQ + 2048;
  const size_t ZERO_LEN = 16384 + 16384 + 2048 + 2048 + 16384;
  const size_t WS_NEED  = OFF_SV + 16384;
  if (ws_size < WS_NEED) return;

  unsigned short* xsb  = (unsigned short*)(ws + OFF_XSB);
  unsigned short* Qb   = (unsigned short*)(ws + OFF_QB);
  unsigned short* xsT  = (unsigned short*)(ws + OFF_XST);
  unsigned short* Gstk = (unsigned short*)(ws + OFF_GSTK);
  unsigned short* Pbf  = (unsigned short*)(ws + OFF_PBF);
  float*          Sf   = (float*)(ws + OFF_SF);
  unsigned short* midb = (unsigned short*)(ws + OFF_MIDB);
  unsigned short* midT = (unsigned short*)(ws + OFF_MIDT);
  unsigned short* wbf  = (unsigned short*)(ws + OFF_WBF);
  unsigned short* wq1x2= (unsigned short*)(ws + OFF_WQ2);
  float* bias5 = (float*)(ws + OFF_B5);
  float* uvec = (float*)(ws + OFF_UV);
  float* wvec = (float*)(ws + OFF_WV);
  float* Zp   = (float*)(ws + OFF_Z);
  float* diag = (float*)(ws + OFF_DIAG);
  float* ksum = (float*)(ws + OFF_KSUM);
  float* bnS  = (float*)(ws + OFF_BNS);
  float* bnQ  = (float*)(ws + OFF_BNQ);
  float* svec = (float*)(ws + OFF_SV);

  hipMemsetAsync(ws + OFF_DIAG, 0, ZERO_LEN, stream);

  k_prep_w  <<<dim3(1024, 5), 256, 0, stream>>>(Wq, Wk, Wv, Wq1, Wk1, wbf);
  k_prep_b  <<<dim3(10),      256, 0, stream>>>(bq, bk, bv, bq1, bk1, bias5);
  k_prep_dup<<<dim3(512),     256, 0, stream>>>(wbf, wq1x2);

  // xs, xs^T, and column-sums in one pass (pos read once)
  k_build_xs<<<dim3(64, 8), 256, 0, stream>>>(x, pos, xsb, xsT, svec);

  // fused projections (Q + chained-KV reductions), 2 blocks/CU
  gemm_proj2<<<dim3(2048), 256, 0, stream>>>(xsb, wbf, bias5, Qb, diag, ksum);

  // u = Wq1 s, w = Wk1 s
  k_uw<<<dim3(2, 8), 256, 0, stream>>>(wbf, svec, uvec, wvec);

  // G = xs^T xs, bf16 stacked partials (split-K x2)
  gemm_G<<<dim3(256), 256, 0, stream>>>(xsT, Gstk);

  // S = Wq1 G Wk1^T + rank-1 corrections
  gemm_P<<<dim3(128), 256, 0, stream>>>(wq1x2, Gstk, Pbf);
  gemm_S<<<dim3(128), 256, 0, stream>>>(Pbf, wbf + 4*262144, bias5, uvec, wvec, Sf);

  // Z row-normalizer
  k_z<<<dim3(8192), 256, 0, stream>>>(Qb, ksum, Zp);

  k_softmax<<<dim3(4096), 64, 0, stream>>>(Sf, midb);
  k_transpose_scale<<<dim3(8, 8, 8), 256, 0, stream>>>(midb, diag, midT);

  // result GEMM + residual + BN-stat epilogue (y in-place over xs_bf)
  gemm8_res<<<dim3(256), 512, 0, stream>>>(Qb, midT, Zp, xsb, gam, bnS, bnQ);

  k_bn_finalize<<<dim3(64, 8, 8), 256, 0, stream>>>(xsb, bnS, bnQ, bnw, bnb, out);
}

// Round 9
// 219.413 us; speedup vs baseline: 1.1991x; 1.1215x over previous
//
#include <hip/hip_runtime.h>
#include <stdint.h>

typedef float f32x4 __attribute__((ext_vector_type(4)));
typedef short bf16x8 __attribute__((ext_vector_type(8)));

__device__ __forceinline__ float bf2f(unsigned short h){
  union { unsigned int u; float f; } v; v.u = ((unsigned int)h) << 16; return v.f;
}
__device__ __forceinline__ unsigned short f2bf(float f){
  union { float f; unsigned int u; } v; v.f = f;
  return (unsigned short)((v.u + 0x7fffu + ((v.u >> 16) & 1u)) >> 16);
}

typedef __attribute__((address_space(1))) const unsigned int ga_u32;
typedef __attribute__((address_space(3))) unsigned int ls_u32;
__device__ __forceinline__ void async_load16(const void* g, void* l){
  __builtin_amdgcn_global_load_lds((ga_u32*)g, (ls_u32*)l, 16, 0, 0);
}

#define CFENCE() asm volatile("" ::: "memory")
#define SB0() __builtin_amdgcn_sched_barrier(0)

// ---------------------------------------------------------------------------
// unified prep: weights->bf16 (5x512x512), biases->packed, wq1x2 dup (from fp32)
__global__ __launch_bounds__(256) void k_prep_all(
    const float* __restrict__ w0, const float* __restrict__ w1,
    const float* __restrict__ w2, const float* __restrict__ w3,
    const float* __restrict__ w4,
    const float* __restrict__ b0, const float* __restrict__ b1,
    const float* __restrict__ b2, const float* __restrict__ b3,
    const float* __restrict__ b4,
    unsigned short* __restrict__ wbf, float* __restrict__ bias5,
    unsigned short* __restrict__ wq1x2)
{
  const int bid = blockIdx.x;
  const int t = threadIdx.x;
  if (bid < 5120){
    int slot = bid >> 10;
    int i = (bid & 1023) * 256 + t;
    const float* w = (slot == 0) ? w0 : (slot == 1) ? w1 :
                     (slot == 2) ? w2 : (slot == 3) ? w3 : w4;
    wbf[(size_t)slot * 262144 + i] = f2bf(w[i]);
  } else if (bid < 5130){
    int i = (bid - 5120) * 256 + t;   // 0..2559
    int s = i >> 9, r = i & 511;
    const float* b = (s == 0) ? b0 : (s == 1) ? b1 : (s == 2) ? b2 :
                     (s == 3) ? b3 : b4;
    bias5[i] = b[r];
  } else {
    int e = bid - 5130;               // 0..511
    #pragma unroll
    for (int rep = 0; rep < 2; rep++){
      int idx = rep*256 + t;
      unsigned short v = f2bf(w3[e*512 + idx]);   // w3 == Wq1 fp32
      wq1x2[(size_t)e*1024 + idx] = v;
      wq1x2[(size_t)e*1024 + 512 + idx] = v;
    }
  }
}

// ---------------------------------------------------------------------------
// build xs_bf[b][l][c], xsT[b][c][l], svec[b][c] partial col-sums.
// pos tile loaded once; loop over all 8 batches. grid (64 lt, 8 ct).
__global__ __launch_bounds__(256) void k_build_xs(
    const float* __restrict__ x, const float* __restrict__ pos,
    unsigned short* __restrict__ xsb, unsigned short* __restrict__ xsT,
    float* __restrict__ svec)
{
  __shared__ float tile[64][65];
  __shared__ unsigned short tile2[64][72];
  __shared__ float sred[256];
  const int lt = blockIdx.x, ct = blockIdx.y;
  const int t = threadIdx.x;
  const int rr = t >> 3, c8 = (t & 7) * 8;
  float pr[16];
  #pragma unroll
  for (int pass = 0; pass < 2; pass++){
    int gl = lt*64 + rr + pass*32;
    f32x4 p0 = *(const f32x4*)(pos + (size_t)gl * 512 + ct*64 + c8);
    f32x4 p1 = *(const f32x4*)(pos + (size_t)gl * 512 + ct*64 + c8 + 4);
    #pragma unroll
    for (int s = 0; s < 4; s++){ pr[pass*8+s] = p0[s]; pr[pass*8+4+s] = p1[s]; }
  }
  for (int b = 0; b < 8; b++){
    #pragma unroll
    for (int pass = 0; pass < 2; pass++){
      int r = rr + pass * 32;
      const float* src = x + ((size_t)b * 512 + ct*64 + r) * 4096 + lt*64 + c8;
      f32x4 v0 = *(const f32x4*)src;
      f32x4 v1 = *(const f32x4*)(src + 4);
      #pragma unroll
      for (int s = 0; s < 4; s++){ tile[r][c8+s] = v0[s]; tile[r][c8+4+s] = v1[s]; }
    }
    __syncthreads();
    #pragma unroll
    for (int pass = 0; pass < 2; pass++){
      int ll = rr + pass * 32;
      int gl = lt*64 + ll;
      bf16x8 hv;
      #pragma unroll
      for (int s = 0; s < 8; s++){
        unsigned short h = f2bf(tile[c8+s][ll] + pr[pass*8+s]);
        hv[s] = (short)h;
        tile2[c8+s][ll] = h;
      }
      *(bf16x8*)(xsb + ((size_t)b * 4096 + gl) * 512 + ct*64 + c8) = hv;
    }
    __syncthreads();
    #pragma unroll
    for (int rep = 0; rep < 2; rep++){
      int c = rep*32 + (t >> 3);
      int l0 = (t & 7) * 8;
      bf16x8 v = *(const bf16x8*)&tile2[c][l0];
      *(bf16x8*)(xsT + ((size_t)b * 512 + ct*64 + c) * 4096 + lt*64 + l0) = v;
    }
    {
      const int c = t & 63, lq = t >> 6;
      float s_ = 0.f;
      #pragma unroll
      for (int j = 0; j < 16; j++) s_ += bf2f(tile2[c][lq*16 + j]);
      sred[t] = s_;
      __syncthreads();
      if (t < 64){
        float ss = sred[t] + sred[t+64] + sred[t+128] + sred[t+192];
        atomicAdd(&svec[b*512 + ct*64 + t], ss);
      }
    }
    __syncthreads();
  }
}

// ---------------------------------------------------------------------------
// Z[row] = 1 / sum_c Q[row,c]*(Ksum[b,c]+eps)
__global__ __launch_bounds__(256) void k_z(
    const unsigned short* __restrict__ Qb, const float* __restrict__ ksum,
    float* __restrict__ Z)
{
  const int row = blockIdx.x * 4 + (threadIdx.x >> 6);
  const int lane = threadIdx.x & 63;
  const int b = row >> 12;
  bf16x8 q = *(const bf16x8*)(Qb + (size_t)row * 512 + lane * 8);
  f32x4 k0 = *(const f32x4*)(ksum + b*512 + lane*8);
  f32x4 k1 = *(const f32x4*)(ksum + b*512 + lane*8 + 4);
  float den = 0.f;
  #pragma unroll
  for (int s = 0; s < 4; s++) den += bf2f((unsigned short)q[s])   * (k0[s] + 1e-6f);
  #pragma unroll
  for (int s = 0; s < 4; s++) den += bf2f((unsigned short)q[4+s]) * (k1[s] + 1e-6f);
  #pragma unroll
  for (int m = 1; m < 64; m <<= 1) den += __shfl_xor(den, m);
  if (lane == 0) Z[row] = 1.0f / den;
}

// ---------------------------------------------------------------------------
// row softmax: S[row][0..511] fp32 -> mid bf16
__global__ __launch_bounds__(64) void k_softmax(
    const float* __restrict__ S, unsigned short* __restrict__ mid)
{
  const size_t row = blockIdx.x;
  const int lane = threadIdx.x;
  const float* p = S + row * 512 + lane * 8;
  f32x4 v0 = *(const f32x4*)p, v1 = *(const f32x4*)(p + 4);
  float mx = v0[0];
  #pragma unroll
  for (int s = 1; s < 4; s++) mx = fmaxf(mx, v0[s]);
  #pragma unroll
  for (int s = 0; s < 4; s++) mx = fmaxf(mx, v1[s]);
  #pragma unroll
  for (int m = 1; m < 64; m <<= 1) mx = fmaxf(mx, __shfl_xor(mx, m));
  float e[8]; float sum = 0.f;
  #pragma unroll
  for (int s = 0; s < 4; s++){ e[s]   = __expf(v0[s] - mx); sum += e[s]; }
  #pragma unroll
  for (int s = 0; s < 4; s++){ e[4+s] = __expf(v1[s] - mx); sum += e[4+s]; }
  #pragma unroll
  for (int m = 1; m < 64; m <<= 1) sum += __shfl_xor(sum, m);
  float inv = 1.0f / sum;
  bf16x8 hv;
  #pragma unroll
  for (int s = 0; s < 8; s++) hv[s] = (short)f2bf(e[s] * inv);
  *(bf16x8*)(mid + row * 512 + lane * 8) = hv;
}

// ---------------------------------------------------------------------------
// mid transpose with diag fold: midT[z][d][c] = mid[z][c][d] * diag[z][c]
__global__ __launch_bounds__(256) void k_transpose_scale(
    const unsigned short* __restrict__ in, const float* __restrict__ diag,
    unsigned short* __restrict__ out)
{
  __shared__ float tile[64][65];
  const int rt = blockIdx.x, ct = blockIdx.y, z = blockIdx.z;
  const unsigned short* src = in  + (size_t)z * 262144;
  unsigned short*       dst = out + (size_t)z * 262144;
  const int t = threadIdx.x;
  const int rr = t >> 3, c8 = (t & 7) * 8;
  #pragma unroll
  for (int pass = 0; pass < 2; pass++){
    int r = rr + pass * 32;
    bf16x8 v = *(const bf16x8*)(src + (size_t)(rt*64 + r) * 512 + ct*64 + c8);
    #pragma unroll
    for (int s = 0; s < 8; s++) tile[r][c8+s] = bf2f((unsigned short)v[s]);
  }
  __syncthreads();
  f32x4 dg0 = *(const f32x4*)(diag + z*512 + rt*64 + c8);
  f32x4 dg1 = *(const f32x4*)(diag + z*512 + rt*64 + c8 + 4);
  #pragma unroll
  for (int pass = 0; pass < 2; pass++){
    int c = rr + pass * 32;
    bf16x8 hv;
    #pragma unroll
    for (int s = 0; s < 4; s++) hv[s]   = (short)f2bf(tile[c8+s][c]   * dg0[s]);
    #pragma unroll
    for (int s = 0; s < 4; s++) hv[4+s] = (short)f2bf(tile[c8+4+s][c] * dg1[s]);
    *(bf16x8*)(dst + (size_t)(ct*64 + c) * 512 + rt*64 + c8) = hv;
  }
}

// ===========================================================================
// 128x128-tile 2-phase GEMM machinery (64KB LDS -> 2 blocks/CU).
// ===========================================================================
#define GEMM_PRE()                                                            \
  const int tid = threadIdx.x;                                                \
  const int lane = tid & 63;                                                  \
  const int wave = tid >> 6;                                                  \
  const int wm = wave >> 1, wn = wave & 1;                                    \
  size_t aoff[4], boff[4]; int ldsq[4];                                       \
  _Pragma("unroll")                                                           \
  for (int i = 0; i < 4; i++){                                                \
    int qq = i*4 + wave;                                                      \
    int ch = qq*64 + lane;                                                    \
    int m  = ch >> 3, p = ch & 7;                                             \
    int lc = p ^ (m & 7);                                                     \
    aoff[i] = (size_t)(m0 + m) * K + lc*8;                                    \
    boff[i] = (size_t)m * K + lc*8;                                           \
    ldsq[i] = qq * 1024;                                                      \
  }                                                                           \
  f32x4 acc[4][4];                                                            \
  const f32x4 vzero = {0.f,0.f,0.f,0.f};                                      \
  _Pragma("unroll")                                                           \
  for (int i = 0; i < 4; i++)                                                 \
    _Pragma("unroll")                                                         \
    for (int j = 0; j < 4; j++) acc[i][j] = vzero;                            \
  int arow[4], brow[4];                                                       \
  _Pragma("unroll")                                                           \
  for (int f = 0; f < 4; f++){                                                \
    arow[f] = (wm*64 + f*16 + (lane & 15)) * 64;                              \
    brow[f] = (wn*64 + f*16 + (lane & 15)) * 64;                              \
  }                                                                           \
  const int kg = lane >> 4;                                                   \
  const int l7 = lane & 7;                                                    \
  const int l15 = lane & 15;

#define GEMM_STAGE2(buf, kt, BB)                                              \
  _Pragma("unroll")                                                           \
  for (int i = 0; i < 4; i++){                                                \
    async_load16(Ae + aoff[i] + (kt)*64, (char*)&smem[(buf)*8192] + ldsq[i]); \
    async_load16((BB) + boff[i] + (kt)*64, (char*)&smem[16384 + (buf)*8192] + ldsq[i]); \
  }

#define GEMM_COMPUTE2(buf, ACC)                                               \
  _Pragma("unroll")                                                           \
  for (int ks = 0; ks < 2; ks++){                                             \
    bf16x8 a[4], b[4];                                                        \
    const int pa = (ks*4 + kg) ^ l7;                                          \
    _Pragma("unroll")                                                         \
    for (int f = 0; f < 4; f++){                                              \
      a[f] = *(const bf16x8*)&smem[(buf)*8192 + arow[f] + pa*8];              \
      b[f] = *(const bf16x8*)&smem[16384 + (buf)*8192 + brow[f] + pa*8];      \
    }                                                                         \
    _Pragma("unroll")                                                         \
    for (int i = 0; i < 4; i++)                                               \
      _Pragma("unroll")                                                       \
      for (int j = 0; j < 4; j++)                                             \
        (ACC)[i][j] = __builtin_amdgcn_mfma_f32_16x16x32_bf16(a[i], b[j], (ACC)[i][j], 0, 0, 0); \
  }

#define GEMM_KLOOP2(nkt, BB)                                                  \
  GEMM_STAGE2(0, 0, BB);                                                      \
  __syncthreads();                                                            \
  { int cur = 0;                                                              \
    for (int kt = 0; kt < (nkt); kt++){                                       \
      if (kt + 1 < (nkt)) { GEMM_STAGE2(cur ^ 1, kt + 1, BB); }               \
      GEMM_COMPUTE2(cur, acc);                                                \
      __syncthreads();                                                        \
      cur ^= 1;                                                               \
    } }

// ===========================================================================
// MEGA kernel: proj (Q + chained KV) + G-syrk + uw, one launch.
// grid = 2320 = 8 XCD-chunks x 290 (32 G + 256 proj + 2 uw).
// ===========================================================================
__global__ __launch_bounds__(256, 2) void k_mega(
    const unsigned short* __restrict__ A,      // xsb
    const unsigned short* __restrict__ xsT,
    const unsigned short* __restrict__ W,
    const float* __restrict__ bias5,
    const float* __restrict__ svec,
    unsigned short* __restrict__ Qb,
    unsigned short* __restrict__ Gstk,
    float* __restrict__ diag, float* __restrict__ ksum,
    float* __restrict__ uvec, float* __restrict__ wvec)
{
  __shared__ unsigned short smem[32768];   // 64KB
  const int bid = blockIdx.x;
  const int xcd = bid & 7, local = bid >> 3;   // local 0..289

  if (local < 32){
    // ---------------- G-syrk path ----------------
    const int gw = xcd*32 + local;               // 0..255
    const int part = gw & 1;
    const int ntile = (gw >> 1) & 3;
    const int mtile = (gw >> 3) & 3;
    const int z = gw >> 5;
    const int m0 = mtile * 128, n0 = ntile * 128;
    const int K = 4096;
    const unsigned short* Ae = xsT + (size_t)z * 2097152 + part * 2048;
    const unsigned short* Be = Ae + (size_t)n0 * 4096;

    GEMM_PRE();
    GEMM_KLOOP2(32, Be);

    #pragma unroll
    for (int j = 0; j < 4; j++){
      const int cl = wn*64 + j*16 + l15;
      #pragma unroll
      for (int i = 0; i < 4; i++){
        const int rb = wm*64 + i*16 + kg*4;
        #pragma unroll
        for (int q = 0; q < 4; q++)
          smem[(rb + q)*136 + cl] = f2bf(acc[i][j][q]);
      }
    }
    __syncthreads();
    #pragma unroll
    for (int rep = 0; rep < 8; rep++){
      const int rl = rep*16 + (tid >> 4);
      const int c0 = (tid & 15) * 8;
      bf16x8 v = *(const bf16x8*)&smem[rl*136 + c0];
      *(bf16x8*)(Gstk + (size_t)z*524288 + (size_t)(m0 + rl)*1024 + part*512 + n0 + c0) = v;
    }
    return;
  }

  if (local >= 288){
    // ---------------- uw path ----------------
    const int uwid = xcd*2 + (local - 288);      // 0..15
    const int sel = uwid & 1, b = uwid >> 1;
    const int t = threadIdx.x;
    float* sv = (float*)(void*)smem;             // 2KB
    sv[t] = svec[b*512 + t]; sv[t+256] = svec[b*512 + t + 256];
    __syncthreads();
    const unsigned short* Wp = W + (size_t)(3 + sel) * 262144;
    float* o = sel ? wvec : uvec;
    #pragma unroll
    for (int rep = 0; rep < 2; rep++){
      int e = rep*256 + t;
      const unsigned short* row = Wp + (size_t)e * 512;
      float acc_ = 0.f;
      for (int ch = 0; ch < 64; ch++){
        bf16x8 v = *(const bf16x8*)(row + ch*8);
        #pragma unroll
        for (int j = 0; j < 8; j++) acc_ += bf2f((unsigned short)v[j]) * sv[ch*8+j];
      }
      o[b*512 + e] = acc_;
    }
    return;
  }

  // ---------------- proj path ----------------
  const int pw = xcd*256 + (local - 32);         // 0..2047
  const int mtile = pw >> 3;                     // 0..255
  const int unit  = pw & 7;
  const int m0 = mtile * 128;
  const int K = 512;
  const unsigned short* Ae = A;

  int mode, cb;
  const unsigned short* BeK; const unsigned short* BeV = W;
  if (unit < 4){ mode = 0; cb = unit*128;     BeK = W + (size_t)cb * 512; }
  else         { mode = 1; cb = (unit-4)*128; BeK = W + 262144 + (size_t)cb * 512;
                                              BeV = W + 524288 + (size_t)cb * 512; }

  GEMM_PRE();

  if (mode == 1){
    const int bz = mtile >> 5;
    GEMM_STAGE2(0, 0, BeK);
    __syncthreads();
    int cur = 0;
    for (int kt = 0; kt < 8; kt++){
      if (kt < 7) { GEMM_STAGE2(cur ^ 1, kt + 1, BeK); }
      else        { GEMM_STAGE2(cur ^ 1, 0, BeV); }
      GEMM_COMPUTE2(cur, acc);
      __syncthreads();
      cur ^= 1;
    }
    GEMM_STAGE2(cur ^ 1, 1, BeV);
    unsigned int kpk[4][4][2];
    #pragma unroll
    for (int j = 0; j < 4; j++){
      const int cj = cb + wn*64 + j*16 + l15;
      const float bb = bias5[512 + cj];
      float ks_ = 0.f;
      #pragma unroll
      for (int i = 0; i < 4; i++){
        #pragma unroll
        for (int h = 0; h < 2; h++){
          float v0 = acc[i][j][2*h]   + bb; v0 = v0 > 0.f ? v0 : 0.f;
          float v1 = acc[i][j][2*h+1] + bb; v1 = v1 > 0.f ? v1 : 0.f;
          unsigned short h0 = f2bf(v0), h1 = f2bf(v1);
          kpk[i][j][h] = (unsigned)h0 | ((unsigned)h1 << 16);
          ks_ += bf2f(h0) + bf2f(h1);
        }
        acc[i][j] = vzero;
      }
      ks_ += __shfl_xor(ks_, 16);
      ks_ += __shfl_xor(ks_, 32);
      if (lane < 16) atomicAdd(&ksum[bz*512 + cj], ks_);
    }
    for (int kt = 0; kt < 8; kt++){
      if (kt >= 1 && kt < 7) { GEMM_STAGE2(cur ^ 1, kt + 1, BeV); }
      GEMM_COMPUTE2(cur, acc);
      __syncthreads();
      cur ^= 1;
    }
    #pragma unroll
    for (int j = 0; j < 4; j++){
      const int cj = cb + wn*64 + j*16 + l15;
      const float bb = bias5[1024 + cj];
      float dv = 0.f;
      #pragma unroll
      for (int i = 0; i < 4; i++){
        #pragma unroll
        for (int h = 0; h < 2; h++){
          float v0 = bf2f(f2bf(acc[i][j][2*h]   + bb));
          float v1 = bf2f(f2bf(acc[i][j][2*h+1] + bb));
          dv += bf2f((unsigned short)(kpk[i][j][h] & 0xffffu)) * v0
              + bf2f((unsigned short)(kpk[i][j][h] >> 16))     * v1;
        }
      }
      dv += __shfl_xor(dv, 16);
      dv += __shfl_xor(dv, 32);
      if (lane < 16) atomicAdd(&diag[bz*512 + cj], dv);
    }
    return;
  }

  GEMM_KLOOP2(8, BeK);

  #pragma unroll
  for (int j = 0; j < 4; j++){
    const int cl = wn*64 + j*16 + l15;
    const float bb = bias5[cb + cl];
    #pragma unroll
    for (int i = 0; i < 4; i++){
      const int rb = wm*64 + i*16 + kg*4;
      #pragma unroll
      for (int q = 0; q < 4; q++){
        float v = acc[i][j][q] + bb; v = v > 0.f ? v : 0.f;
        smem[(rb + q)*136 + cl] = f2bf(v);
      }
    }
  }
  __syncthreads();
  #pragma unroll
  for (int rep = 0; rep < 8; rep++){
    const int rl = rep*16 + (tid >> 4);
    const int c0 = (tid & 15) * 8;
    bf16x8 v = *(const bf16x8*)&smem[rl*136 + c0];
    *(bf16x8*)(Qb + (size_t)(m0 + rl) * 512 + cb + c0) = v;
  }
}

// ---------------------------------------------------------------------------
// P[z] = Wq1 @ (G0+G1) via stacked K=1024 (A = wq1x2, Bt = Gstack rows)
__global__ __launch_bounds__(256) void gemm_P(
    const unsigned short* __restrict__ Wq1x2,
    const unsigned short* __restrict__ Gstk,
    unsigned short* __restrict__ P)
{
  __shared__ unsigned short smem[32768];
  const int bid = blockIdx.x;
  const int wgid = (bid & 7) * 16 + (bid >> 3);    // 128 blocks
  const int z = wgid >> 4;
  const int mtile = (wgid >> 2) & 3, ntile = wgid & 3;
  const int m0 = mtile * 128, n0 = ntile * 128;
  const int K = 1024;
  const unsigned short* Ae = Wq1x2;
  const unsigned short* Be = Gstk + (size_t)z * 524288 + (size_t)n0 * 1024;

  GEMM_PRE();
  GEMM_KLOOP2(16, Be);

  #pragma unroll
  for (int j = 0; j < 4; j++){
    const int cl = wn*64 + j*16 + l15;
    #pragma unroll
    for (int i = 0; i < 4; i++){
      const int rb = wm*64 + i*16 + kg*4;
      #pragma unroll
      for (int q = 0; q < 4; q++)
        smem[(rb + q)*136 + cl] = f2bf(acc[i][j][q]);
    }
  }
  __syncthreads();
  #pragma unroll
  for (int rep = 0; rep < 8; rep++){
    const int rl = rep*16 + (tid >> 4);
    const int c0 = (tid & 15) * 8;
    bf16x8 v = *(const bf16x8*)&smem[rl*136 + c0];
    *(bf16x8*)(P + (size_t)z * 262144 + (size_t)(m0 + rl) * 512 + n0 + c0) = v;
  }
}

// ---------------------------------------------------------------------------
// S[z] = P[z] @ Wk1^T + u bk1^T + bq1 w^T + L bq1 bk1^T  (fp32 out)
__global__ __launch_bounds__(256) void gemm_S(
    const unsigned short* __restrict__ P,
    const unsigned short* __restrict__ Wk1b,
    const float* __restrict__ bias5,
    const float* __restrict__ u, const float* __restrict__ w,
    float* __restrict__ Sf)
{
  __shared__ unsigned short smem[32768];
  const int bid = blockIdx.x;
  const int wgid = (bid & 7) * 16 + (bid >> 3);    // 128 blocks
  const int z = wgid >> 4;
  const int mtile = (wgid >> 2) & 3, ntile = wgid & 3;
  const int m0 = mtile * 128, n0 = ntile * 128;
  const int K = 512;
  const unsigned short* Ae = P + (size_t)z * 262144;
  const unsigned short* Be = Wk1b + (size_t)n0 * 512;

  GEMM_PRE();
  GEMM_KLOOP2(8, Be);

  #pragma unroll
  for (int j = 0; j < 4; j++){
    int cd = n0 + wn*64 + j*16 + l15;
    float bkv = bias5[2048 + cd];
    float wv  = w[z*512 + cd] + 4096.0f * bkv;
    #pragma unroll
    for (int i = 0; i < 4; i++){
      int r = m0 + wm*64 + i*16 + kg*4;
      #pragma unroll
      for (int q = 0; q < 4; q++){
        int rr = r + q;
        float uq  = u[z*512 + rr];
        float bqv = bias5[1536 + rr];
        Sf[(size_t)z * 262144 + (size_t)rr * 512 + cd] =
            acc[i][j][q] + uq * bkv + bqv * wv;
      }
    }
  }
}

// ===========================================================================
// 256x256-tile, 8-wave, 8-phase counted-vmcnt GEMM (result GEMM only).
// ===========================================================================
#define G8_PRE(AE)                                                            \
  const int t = threadIdx.x;                                                  \
  const int lane = t & 63;                                                    \
  const int wave = t >> 6;                                                    \
  const int wm = wave >> 2, wn = wave & 3;                                    \
  const int l15 = lane & 15, kg = lane >> 4;                                  \
  const int lcw = ((t & 7) ^ ((t >> 3) & 7)) * 8;                             \
  const unsigned short* a_src = (AE) + (size_t)(m0 + (t >> 3)) * 512 + lcw;   \
  f32x4 acc[8][4];                                                            \
  const f32x4 vzero = {0.f,0.f,0.f,0.f};                                      \
  _Pragma("unroll")                                                           \
  for (int i = 0; i < 8; i++)                                                 \
    _Pragma("unroll")                                                         \
    for (int j = 0; j < 4; j++) acc[i][j] = vzero;                            \
  bf16x8 af[4][2], bf[4][2];

#define STAGE_A(D,H,TT) do{                                                   \
  async_load16(a_src + (H)*65536 + (TT)*64,                                   \
               (char*)smem + ((D)*16384 + (H)*8192 + t*8)*2);                 \
  async_load16(a_src + (H)*65536 + 32768 + (TT)*64,                           \
               (char*)smem + ((D)*16384 + (H)*8192 + 4096 + t*8)*2);          \
}while(0)

#define STAGE_B(D,H,TT) do{                                                   \
  async_load16(b_src + (H)*65536 + (TT)*64,                                   \
               (char*)smem + (32768 + (D)*16384 + (H)*8192 + t*8)*2);         \
  async_load16(b_src + (H)*65536 + 32768 + (TT)*64,                           \
               (char*)smem + (32768 + (D)*16384 + (H)*8192 + 4096 + t*8)*2);  \
}while(0)

#define READ_A(D, MH) do{                                                     \
  _Pragma("unroll")                                                           \
  for (int mfl = 0; mfl < 4; ++mfl){                                          \
    const int rl = ((MH)*4 + mfl)*16 + l15;                                   \
    _Pragma("unroll")                                                         \
    for (int ks = 0; ks < 2; ++ks){                                           \
      const int ck = (ks*4 + kg) ^ (rl & 7);                                  \
      af[mfl][ks] = *(const bf16x8*)&smem[(D)*16384 + wm*8192 + rl*64 + ck*8];\
    }                                                                         \
  }                                                                           \
}while(0)

#define READ_B(D, NP) do{                                                     \
  _Pragma("unroll")                                                           \
  for (int nfl = 0; nfl < 2; ++nfl){                                          \
    const int nf = (NP)*2 + nfl;                                              \
    const int rbl = (wn & 1)*64 + nf*16 + l15;                                \
    _Pragma("unroll")                                                         \
    for (int ks = 0; ks < 2; ++ks){                                           \
      const int ck = (ks*4 + kg) ^ (rbl & 7);                                 \
      bf[nf][ks] = *(const bf16x8*)&smem[32768 + (D)*16384 + (wn>>1)*8192 + rbl*64 + ck*8]; \
    }                                                                         \
  }                                                                           \
}while(0)

#define QUAD(MH, NP)                                                          \
  _Pragma("unroll")                                                           \
  for (int mfl = 0; mfl < 4; ++mfl)                                           \
    _Pragma("unroll")                                                         \
    for (int nfl = 0; nfl < 2; ++nfl)                                         \
      _Pragma("unroll")                                                       \
      for (int ks = 0; ks < 2; ++ks)                                          \
        acc[(MH)*4+mfl][(NP)*2+nfl] = __builtin_amdgcn_mfma_f32_16x16x32_bf16(\
            af[mfl][ks], bf[(NP)*2+nfl][ks], acc[(MH)*4+mfl][(NP)*2+nfl], 0,0,0);

#define PH_MID()  CFENCE(); __builtin_amdgcn_s_barrier();                     \
  __builtin_amdgcn_s_setprio(1); SB0()
#define PH_END()  SB0(); __builtin_amdgcn_s_setprio(0); CFENCE();             \
  __builtin_amdgcn_s_barrier(); CFENCE()
#define PH_END_VM4() SB0(); __builtin_amdgcn_s_setprio(0);                    \
  asm volatile("s_waitcnt vmcnt(4)" ::: "memory");                            \
  __builtin_amdgcn_s_barrier(); CFENCE()
#define PH_END_VM0() SB0(); __builtin_amdgcn_s_setprio(0);                    \
  asm volatile("s_waitcnt vmcnt(0)" ::: "memory");                            \
  __builtin_amdgcn_s_barrier(); CFENCE()

#define G8_KLOOP()                                                            \
  STAGE_A(0,0,0); STAGE_A(0,1,0); STAGE_B(0,0,0); STAGE_B(0,1,0);             \
  STAGE_B(1,0,1); STAGE_B(1,1,1);                                             \
  asm volatile("s_waitcnt vmcnt(4)" ::: "memory");                            \
  __builtin_amdgcn_s_barrier(); CFENCE();                                     \
  for (int it = 0; it < 3; ++it){                                             \
    const int t1 = 2*it + 1, t2 = 2*it + 2, t3 = 2*it + 3;                    \
    READ_A(0,0); READ_B(0,0); STAGE_A(1,0,t1);                                \
    PH_MID(); QUAD(0,0); PH_END();                                            \
    READ_B(0,1); STAGE_A(1,1,t1);                                             \
    PH_MID(); QUAD(0,1); PH_END();                                            \
    READ_A(0,1); STAGE_B(0,0,t2);                                             \
    PH_MID(); QUAD(1,0); PH_END();                                            \
    STAGE_A(0,0,t2);                                                          \
    PH_MID(); QUAD(1,1); PH_END_VM4();                                        \
    READ_A(1,0); READ_B(1,0); STAGE_A(0,1,t2);                                \
    PH_MID(); QUAD(0,0); PH_END();                                            \
    READ_B(1,1); STAGE_B(0,1,t2);                                             \
    PH_MID(); QUAD(0,1); PH_END();                                            \
    READ_A(1,1); STAGE_B(1,0,t3);                                             \
    PH_MID(); QUAD(1,0); PH_END();                                            \
    STAGE_B(1,1,t3);                                                          \
    PH_MID(); QUAD(1,1); PH_END_VM4();                                        \
  }                                                                           \
  { READ_A(0,0); READ_B(0,0); STAGE_A(1,0,7);                                 \
    PH_MID(); QUAD(0,0); PH_END();                                            \
    READ_B(0,1); STAGE_A(1,1,7);                                              \
    PH_MID(); QUAD(0,1); PH_END();                                            \
    READ_A(0,1);                                                              \
    PH_MID(); QUAD(1,0); PH_END();                                            \
    PH_MID(); QUAD(1,1); PH_END_VM0();                                        \
    READ_A(1,0); READ_B(1,0);                                                 \
    PH_MID(); QUAD(0,0); PH_END();                                            \
    READ_B(1,1);                                                              \
    PH_MID(); QUAD(0,1); PH_END();                                            \
    READ_A(1,1);                                                              \
    PH_MID(); QUAD(1,0); PH_END();                                            \
    PH_MID(); QUAD(1,1); PH_END(); }

// ---------------------------------------------------------------------------
// result GEMM: y = xs + gamma*Z[l]*(Q @ midT'^T) in-place + BN stats.
__global__ __launch_bounds__(512, 2) void gemm8_res(
    const unsigned short* __restrict__ A,
    const unsigned short* __restrict__ Bt,
    const float* __restrict__ Zp,
    unsigned short* __restrict__ outh,
    const float* __restrict__ gamma_p,
    float* __restrict__ bnS, float* __restrict__ bnQ)
{
  __shared__ unsigned short smem[65536];
  __shared__ float zbuf[256];
  const int bid = blockIdx.x;
  const int wgid = (bid & 7) * 32 + (bid >> 3);   // 256 % 8 == 0
  const int mtile = wgid >> 1;
  const int ntile = wgid & 1;
  const int m0 = mtile * 256;
  const int nc0 = ntile * 256;

  G8_PRE(A);
  const unsigned short* b_src =
      Bt + (size_t)(mtile >> 4) * 262144 + (size_t)(nc0 + (t >> 3)) * 512 + lcw;

  G8_KLOOP();

  const float g = gamma_p[0];
  __syncthreads();
  if (t < 256) zbuf[t] = Zp[m0 + t];
  __syncthreads();
  #pragma unroll
  for (int nf = 0; nf < 4; nf++){
    int cl = wn*64 + nf*16 + l15;
    #pragma unroll
    for (int mf = 0; mf < 8; mf++){
      int rbase = wm*128 + mf*16 + kg*4;
      #pragma unroll
      for (int q = 0; q < 4; q++){
        int rl = rbase + q;
        smem[rl*256 + (cl ^ (((rl >> 2) & 3) << 4))] =
            f2bf(g * zbuf[rl] * acc[mf][nf][q]);
      }
    }
  }
  __syncthreads();
  float sc[8] = {0.f,0.f,0.f,0.f,0.f,0.f,0.f,0.f};
  float sq[8] = {0.f,0.f,0.f,0.f,0.f,0.f,0.f,0.f};
  const int c0 = (t & 31) * 8;
  #pragma unroll
  for (int rep = 0; rep < 16; rep++){
    int rl = rep*16 + (t >> 5);
    bf16x8 ga = *(const bf16x8*)&smem[rl*256 + (c0 ^ (((rl >> 2) & 3) << 4))];
    size_t gidx = (size_t)(m0 + rl) * 512 + nc0 + c0;
    bf16x8 xv = *(const bf16x8*)(outh + gidx);
    bf16x8 yv;
    #pragma unroll
    for (int j = 0; j < 8; j++){
      float y = bf2f((unsigned short)xv[j]) + bf2f((unsigned short)ga[j]);
      yv[j] = (short)f2bf(y);
      sc[j] += y; sq[j] += y * y;
    }
    *(bf16x8*)(outh + gidx) = yv;
  }
  __syncthreads();
  float* red = (float*)(void*)smem;
  const int tg = t >> 5;
  f32x4 s0 = {sc[0],sc[1],sc[2],sc[3]}, s1 = {sc[4],sc[5],sc[6],sc[7]};
  f32x4 q0 = {sq[0],sq[1],sq[2],sq[3]}, q1 = {sq[4],sq[5],sq[6],sq[7]};
  *(f32x4*)&red[tg*256 + c0]        = s0;  *(f32x4*)&red[tg*256 + c0 + 4]        = s1;
  *(f32x4*)&red[4096 + tg*256 + c0] = q0;  *(f32x4*)&red[4096 + tg*256 + c0 + 4] = q1;
  __syncthreads();
  if (t < 256){
    float ss = 0.f, qq = 0.f;
    #pragma unroll
    for (int gg = 0; gg < 16; gg++){
      ss += red[gg*256 + t];
      qq += red[4096 + gg*256 + t];
    }
    atomicAdd(&bnS[nc0 + t], ss);
    atomicAdd(&bnQ[nc0 + t], qq);
  }
}

// ---------------------------------------------------------------------------
// finalize: y[b][l][c] bf16 -> out[b][c][l] fp32, BN affine + relu
__global__ __launch_bounds__(256) void k_bn_finalize(
    const unsigned short* __restrict__ y, const float* __restrict__ bnS,
    const float* __restrict__ bnQ, const float* __restrict__ bnw,
    const float* __restrict__ bnb, float* __restrict__ out)
{
  __shared__ float tile[64][65];
  __shared__ float scale_s[64], shift_s[64];
  const int lt = blockIdx.x, ct = blockIdx.y, b = blockIdx.z;
  const int t = threadIdx.x;
  if (t < 64){
    int c = ct*64 + t;
    float s = bnS[c], q = bnQ[c];
    float mean = s * (1.0f / 32768.0f);
    float var  = q * (1.0f / 32768.0f) - mean * mean;
    float inv  = rsqrtf(var + 1e-5f);
    float scv  = bnw[c] * inv;
    scale_s[t] = scv;
    shift_s[t] = bnb[c] - mean * scv;
  }
  const int rr = t >> 3, c8 = (t & 7) * 8;
  #pragma unroll
  for (int pass = 0; pass < 2; pass++){
    int l = rr + pass * 32;
    bf16x8 v = *(const bf16x8*)(y + ((size_t)b * 4096 + lt*64 + l) * 512 + ct*64 + c8);
    #pragma unroll
    for (int s = 0; s < 8; s++) tile[l][c8+s] = bf2f((unsigned short)v[s]);
  }
  __syncthreads();
  #pragma unroll
  for (int pass = 0; pass < 2; pass++){
    int c = rr + pass * 32;
    float scv = scale_s[c], sh = shift_s[c];
    f32x4 o0, o1;
    #pragma unroll
    for (int s = 0; s < 4; s++){
      float v = tile[c8+s][c] * scv + sh;     o0[s] = v > 0.f ? v : 0.f;
      float w = tile[c8+4+s][c] * scv + sh;   o1[s] = w > 0.f ? w : 0.f;
    }
    float* dp = out + ((size_t)b * 512 + ct*64 + c) * 4096 + lt*64 + c8;
    *(f32x4*)dp = o0;
    *(f32x4*)(dp + 4) = o1;
  }
}

// ---------------------------------------------------------------------------
extern "C" void kernel_launch(void* const* d_in, const int* in_sizes, int n_in,
                              void* d_out, int out_size, void* d_ws, size_t ws_size,
                              hipStream_t stream)
{
  const float* x    = (const float*)d_in[0];
  const float* pos  = (const float*)d_in[1];
  const float* Wq   = (const float*)d_in[2];
  const float* bq   = (const float*)d_in[3];
  const float* Wk   = (const float*)d_in[4];
  const float* bk   = (const float*)d_in[5];
  const float* Wv   = (const float*)d_in[6];
  const float* bv   = (const float*)d_in[7];
  const float* Wq1  = (const float*)d_in[8];
  const float* bq1  = (const float*)d_in[9];
  const float* Wk1  = (const float*)d_in[10];
  const float* bk1  = (const float*)d_in[11];
  const float* gam  = (const float*)d_in[12];
  const float* bnw  = (const float*)d_in[13];
  const float* bnb  = (const float*)d_in[14];
  float* out = (float*)d_out;
  char* ws = (char*)d_ws;

  const size_t MB = 1ull << 20;
  const size_t OFF_XSB  = 0;                  // 32MB xs_bf -> y in-place
  const size_t OFF_QB   = 32*MB;              // 32MB Q
  const size_t OFF_XST  = 64*MB;              // 32MB xs^T [8][512][4096]
  const size_t OFF_GSTK = 96*MB;              // 8MB  Gstack bf16 [8][512][1024]
  const size_t OFF_PBF  = 104*MB;             // 4MB  P bf16
  const size_t OFF_SF   = 108*MB;             // 8MB  S fp32
  const size_t OFF_MIDB = 116*MB;             // 4MB  mid bf16
  const size_t OFF_MIDT = 120*MB;             // 4MB  midT' bf16 (diag-scaled)
  const size_t OFF_WBF  = 124*MB;             // 2.5MB
  const size_t OFF_WQ2  = 127*MB;             // 1MB  Wq1 duplicated [512][1024]
  const size_t OFF_B5   = 128*MB + 512*1024;  // 10KB
  const size_t OFF_UV   = 129*MB;             // 16KB u
  const size_t OFF_WV   = OFF_UV + 16384;     // 16KB w
  const size_t OFF_Z    = OFF_WV + 16384;     // 128KB Z fp32
  const size_t OFF_DIAG = 130*MB;             // zeroed region start
  const size_t OFF_KSUM = OFF_DIAG + 16384;
  const size_t OFF_BNS  = OFF_KSUM + 16384;
  const size_t OFF_BNQ  = OFF_BNS + 2048;
  const size_t OFF_SV   = OFF_BNQ + 2048;
  const size_t ZERO_LEN = 16384 + 16384 + 2048 + 2048 + 16384;
  const size_t WS_NEED  = OFF_SV + 16384;
  if (ws_size < WS_NEED) return;

  unsigned short* xsb  = (unsigned short*)(ws + OFF_XSB);
  unsigned short* Qb   = (unsigned short*)(ws + OFF_QB);
  unsigned short* xsT  = (unsigned short*)(ws + OFF_XST);
  unsigned short* Gstk = (unsigned short*)(ws + OFF_GSTK);
  unsigned short* Pbf  = (unsigned short*)(ws + OFF_PBF);
  float*          Sf   = (float*)(ws + OFF_SF);
  unsigned short* midb = (unsigned short*)(ws + OFF_MIDB);
  unsigned short* midT = (unsigned short*)(ws + OFF_MIDT);
  unsigned short* wbf  = (unsigned short*)(ws + OFF_WBF);
  unsigned short* wq1x2= (unsigned short*)(ws + OFF_WQ2);
  float* bias5 = (float*)(ws + OFF_B5);
  float* uvec = (float*)(ws + OFF_UV);
  float* wvec = (float*)(ws + OFF_WV);
  float* Zp   = (float*)(ws + OFF_Z);
  float* diag = (float*)(ws + OFF_DIAG);
  float* ksum = (float*)(ws + OFF_KSUM);
  float* bnS  = (float*)(ws + OFF_BNS);
  float* bnQ  = (float*)(ws + OFF_BNQ);
  float* svec = (float*)(ws + OFF_SV);

  hipMemsetAsync(ws + OFF_DIAG, 0, ZERO_LEN, stream);

  // unified prep (weights bf16, biases, wq1x2 straight from fp32 Wq1)
  k_prep_all<<<dim3(5642), 256, 0, stream>>>(Wq, Wk, Wv, Wq1, Wk1,
                                             bq, bk, bv, bq1, bk1,
                                             wbf, bias5, wq1x2);

  // xs, xs^T, and column-sums in one pass (pos read once)
  k_build_xs<<<dim3(64, 8), 256, 0, stream>>>(x, pos, xsb, xsT, svec);

  // MEGA: proj (Q + chained-KV) + G-syrk + uw co-scheduled in one launch
  k_mega<<<dim3(2320), 256, 0, stream>>>(xsb, xsT, wbf, bias5, svec,
                                         Qb, Gstk, diag, ksum, uvec, wvec);

  // Z row-normalizer
  k_z<<<dim3(8192), 256, 0, stream>>>(Qb, ksum, Zp);

  // S = Wq1 G Wk1^T + rank-1 corrections
  gemm_P<<<dim3(128), 256, 0, stream>>>(wq1x2, Gstk, Pbf);
  gemm_S<<<dim3(128), 256, 0, stream>>>(Pbf, wbf + 4*262144, bias5, uvec, wvec, Sf);

  k_softmax<<<dim3(4096), 64, 0, stream>>>(Sf, midb);
  k_transpose_scale<<<dim3(8, 8, 8), 256, 0, stream>>>(midb, diag, midT);

  // result GEMM + residual + BN-stat epilogue (y in-place over xs_bf)
  gemm8_res<<<dim3(256), 512, 0, stream>>>(Qb, midT, Zp, xsb, gam, bnS, bnQ);

  k_bn_finalize<<<dim3(64, 8, 8), 256, 0, stream>>>(xsb, bnS, bnQ, bnw, bnb, out);
}